// Round 1
// baseline (21805.011 us; speedup 1.0000x reference)
//
#include <hip/hip_runtime.h>
#include <stdint.h>
#include <stddef.h>

#define HH 3840
#define AH 1920
#define NI 18
#define NT 256
#define NBATCH 64
#define KMAX 224
#define NR 60        // rows per block
#define NB 16        // batches per group
#define NGROUP 8     // 2 areas * 4 batch-groups
#define PRODUCERS 32u
#define NBLOCKS 256
#define NTHREADS 1024

// ---- ws layout (bytes) ----
#define ENT_BYTES ((size_t)HH * KMAX * 4)            // 3,440,640
#define CNT_BYTES ((size_t)HH * 4)                   // 15,360
#define XT_BYTES  ((size_t)NT * NI * NBATCH * 4)     // 1,179,648
#define HT_ELEMS  ((size_t)NGROUP * AH * NB)         // u16 elems per buffer = 245,760
#define HT_BYTES  (2 * HT_ELEMS * 2)                 // 983,040 (double buffered)
#define CTR_ELEMS ((size_t)(NT + 1) * NGROUP)        // 2,056

#define SMEM_BYTES 125232

__device__ __forceinline__ uint16_t f32_to_bf16(float f) {
    uint32_t u = __float_as_uint(f);
    return (uint16_t)((u + 0x7fffu + ((u >> 16) & 1u)) >> 16);
}

__global__ void init_ws_kernel(uint32_t* __restrict__ ctr, uint32_t* __restrict__ ht0) {
    size_t i = (size_t)blockIdx.x * blockDim.x + threadIdx.x;
    if (i < CTR_ELEMS) ctr[i] = 0;
    if (i < HT_ELEMS / 2) ht0[i] = 0;   // zero h buffer 0 (h_{-1} = 0)
}

__global__ void build_ell_kernel(const float* __restrict__ Whh, const float* __restrict__ mask,
                                 uint32_t* __restrict__ ent, uint32_t* __restrict__ cnt) {
    int d = blockIdx.x * blockDim.x + threadIdx.x;
    if (d >= HH) return;
    int area = (d >= AH) ? 1 : 0;
    const float* mrow = mask + (size_t)d * HH + (size_t)area * AH;
    const float* wrow = Whh + (size_t)d * HH + (size_t)area * AH;
    uint32_t* erow = ent + (size_t)d * KMAX;
    uint32_t n = 0;
    for (int c = 0; c < AH; ++c) {
        float m = mrow[c];
        if (m != 0.0f) {
            float w = wrow[c] * m;
            if (n < KMAX) erow[n] = ((uint32_t)c << 16) | (uint32_t)f32_to_bf16(w);
            n++;
        }
    }
    cnt[d] = (n < KMAX) ? n : KMAX;
}

__global__ void xt_kernel(const float* __restrict__ x, float* __restrict__ xT) {
    int i = blockIdx.x * blockDim.x + threadIdx.x;  // over NT*NI*NBATCH, layout [t][i][b]
    if (i >= NT * NI * NBATCH) return;
    int b = i % NBATCH;
    int rest = i / NBATCH;
    int ii = rest % NI;
    int t = rest / NI;
    xT[i] = x[((size_t)b * NT + t) * NI + ii];
}

__global__ __launch_bounds__(NTHREADS, 4) void rnn_kernel(
    const uint32_t* __restrict__ ent, const uint32_t* __restrict__ cnt,
    const float* __restrict__ xT, uint16_t* __restrict__ hT,
    uint32_t* __restrict__ ctr, const float* __restrict__ Wih,
    const float* __restrict__ bih, const float* __restrict__ bhh,
    float* __restrict__ out)
{
    extern __shared__ char smem[];
    uint16_t* hlds  = (uint16_t*)smem;                          // [AH*NB] bf16, 61440 B
    uint32_t* entl  = (uint32_t*)(smem + 61440);                // [NR*KMAX], 53760 B
    float*    wihl  = (float*)(smem + 61440 + 53760);           // [NR*NI]
    float*    xtl   = wihl + NR * NI;                           // [NI*NB]
    float*    biasl = xtl + NI * NB;                            // [NR]
    float*    hnew  = biasl + NR;                               // [NR*17] (padded)
    uint32_t* cntl  = (uint32_t*)(hnew + NR * 17);              // [NR]

    const int tid = threadIdx.x;
    const int bid = blockIdx.x;
    const int G   = bid & 7;    // group 0..7  (== XCD residue under round-robin dispatch)
    const int rb  = bid >> 3;   // 0..31 row-block within group
    const int a   = G >> 2;     // area
    const int g   = G & 3;      // batch-group
    const int row0 = rb * NR;           // local row within area
    const int Rg0  = a * AH + row0;     // global row

    // ---- step-invariant staging (once) ----
    {
        const uint4* esrc = (const uint4*)(ent + (size_t)Rg0 * KMAX);
        uint4* edst = (uint4*)entl;
        for (int i = tid; i < NR * KMAX / 4; i += NTHREADS) edst[i] = esrc[i];
        for (int i = tid; i < NR * NI; i += NTHREADS) wihl[i] = Wih[(size_t)Rg0 * NI + i];
        for (int i = tid; i < NR; i += NTHREADS) {
            biasl[i] = bih[Rg0 + i] + bhh[Rg0 + i];
            cntl[i] = cnt[Rg0 + i];
        }
    }

    const int wv   = tid >> 6;    // wave 0..15
    const int lane = tid & 63;
    const int kk   = lane >> 4;   // 0..3 : k-parallel stripe
    const int b    = lane & 15;   // 0..15: batch within group

    for (int t = 0; t < NT; ++t) {
        if (t > 0) {
            if (tid == 0) {
                while (__hip_atomic_load(&ctr[(size_t)t * NGROUP + G], __ATOMIC_ACQUIRE,
                                         __HIP_MEMORY_SCOPE_AGENT) < PRODUCERS)
                    __builtin_amdgcn_s_sleep(8);
            }
            __syncthreads();
        }
        // stage h slab (bf16 [AH][NB] = 61440 B = 3840 uint4)
        {
            const uint4* src = (const uint4*)(hT + (size_t)(t & 1) * HT_ELEMS + (size_t)G * AH * NB);
            uint4* dst4 = (uint4*)hlds;
            for (int i = tid; i < 3840; i += NTHREADS) dst4[i] = src[i];
        }
        // stage x_t slice for this batch-group
        for (int i = tid; i < NI * NB; i += NTHREADS) {
            int ii = i / NB, bb = i % NB;
            xtl[i] = xT[((size_t)t * NI + ii) * NBATCH + g * NB + bb];
        }
        __syncthreads();

        // compute rows: wave handles rows wv, wv+16, ...
        for (int r = wv; r < NR; r += 16) {
            const uint32_t* ep = entl + r * KMAX;
            const int n = (int)cntl[r];
            float acc = 0.f;
            #pragma unroll 4
            for (int k = kk; k < n; k += 4) {
                uint32_t e = ep[k];
                float w = __uint_as_float(e << 16);                         // bf16 -> f32
                float h = __uint_as_float((uint32_t)hlds[((e >> 16) << 4) + b] << 16);
                acc = fmaf(w, h, acc);
            }
            // input projection folded in (split over kk stripes)
            for (int i = kk; i < NI; i += 4)
                acc = fmaf(xtl[i * NB + b], wihl[r * NI + i], acc);
            acc += __shfl_xor(acc, 16, 64);
            acc += __shfl_xor(acc, 32, 64);
            float hv = fmaxf(acc + biasl[r], 0.f);
            if (kk == 0) hnew[r * 17 + b] = hv;
        }
        __syncthreads();

        // publish next h slab (bf16)
        {
            uint16_t* dst = hT + (size_t)((t + 1) & 1) * HT_ELEMS + (size_t)G * AH * NB
                            + (size_t)row0 * NB;
            for (int i = tid; i < NR * NB; i += NTHREADS) {
                int r = i >> 4, bb = i & 15;
                dst[i] = f32_to_bf16(hnew[r * 17 + bb]);
            }
        }
        __threadfence();
        __syncthreads();
        if (tid == 0)
            __hip_atomic_fetch_add(&ctr[(size_t)(t + 1) * NGROUP + G], 1u, __ATOMIC_RELEASE,
                                   __HIP_MEMORY_SCOPE_AGENT);
        // write output tile (off critical path)
        for (int i = tid; i < NB * NR; i += NTHREADS) {
            int bb = i / NR, d = i % NR;
            out[(((size_t)(g * NB + bb)) * NT + t) * HH + (size_t)a * AH + row0 + d]
                = hnew[d * 17 + bb];
        }
    }
}

extern "C" void kernel_launch(void* const* d_in, const int* in_sizes, int n_in,
                              void* d_out, int out_size, void* d_ws, size_t ws_size,
                              hipStream_t stream)
{
    const float* x    = (const float*)d_in[0];
    const float* Wih  = (const float*)d_in[1];
    const float* bih  = (const float*)d_in[2];
    const float* Whh  = (const float*)d_in[3];
    const float* bhh  = (const float*)d_in[4];
    const float* mask = (const float*)d_in[5];
    float* out = (float*)d_out;

    char* ws = (char*)d_ws;
    uint32_t* ent = (uint32_t*)(ws);
    uint32_t* cnt = (uint32_t*)(ws + ENT_BYTES);
    float*    xT  = (float*)(ws + ENT_BYTES + CNT_BYTES);
    uint16_t* hT  = (uint16_t*)(ws + ENT_BYTES + CNT_BYTES + XT_BYTES);
    uint32_t* ctr = (uint32_t*)(ws + ENT_BYTES + CNT_BYTES + XT_BYTES + HT_BYTES);

    init_ws_kernel<<<480, 256, 0, stream>>>(ctr, (uint32_t*)hT);
    build_ell_kernel<<<(HH + 255) / 256, 256, 0, stream>>>(Whh, mask, ent, cnt);
    xt_kernel<<<(NT * NI * NBATCH + 255) / 256, 256, 0, stream>>>(x, xT);

    hipFuncSetAttribute((const void*)rnn_kernel,
                        hipFuncAttributeMaxDynamicSharedMemorySize, SMEM_BYTES);

    void* args[] = {(void*)&ent, (void*)&cnt, (void*)&xT, (void*)&hT, (void*)&ctr,
                    (void*)&Wih, (void*)&bih, (void*)&bhh, (void*)&out};
    hipLaunchCooperativeKernel((const void*)rnn_kernel, dim3(NBLOCKS), dim3(NTHREADS),
                               args, SMEM_BYTES, stream);
}

// Round 3
// 4838.897 us; speedup vs baseline: 4.5062x; 4.5062x over previous
//
#include <hip/hip_runtime.h>
#include <stdint.h>
#include <stddef.h>

#define HH 3840
#define AH 1920
#define NI 18
#define NT 256
#define NBATCH 64
#define KMAX 224      // ELL capacity (global), incl. 18 input entries
#define KPAD 228      // LDS row stride (bank spread: 228 % 32 = 4)
#define NRW 60        // rows per block
#define NB 16         // batches per group
#define COLS 1920
#define COLT 1938     // 1920 h cols + 18 x cols
#define NBLOCKS 256
#define NTHREADS 1024

// ---- ws layout (bytes) ----
#define ENT_BYTES ((size_t)HH * KMAX * 4)            // 3,440,640
#define CNT_BYTES ((size_t)HH * 4)                   // 15,360
#define XT_BYTES  ((size_t)NT * NI * NBATCH * 4)     // 1,179,648
#define HT_HALF   ((size_t)8 * AH * NB)              // u16 elems per buffer = 245,760
#define HT_BYTES  (2 * HT_HALF * 2)                  // 983,040 (double buffered)
#define CTR_ELEMS 2080                               // flags + xcdcnt(8)@2056 + gbar@2064

// ---- LDS layout (bytes) ----
#define OFF_HLDS  0
#define HLDS_B    (COLT * 32)            // 62,016  f16 [COLT][16]
#define OFF_ENTL  (OFF_HLDS + HLDS_B)    // 62,016
#define ENTL_B    (NRW * KPAD * 4)       // 54,720
#define OFF_HNEW  (OFF_ENTL + ENTL_B)    // 116,736
#define HNEW_B    (NRW * 17 * 4)         // 4,080
#define OFF_BIAS  (OFF_HNEW + HNEW_B)    // 120,816
#define OFF_CNT   (OFF_BIAS + NRW * 4)   // 121,056
#define SMEM_BYTES (OFF_CNT + NRW * 4)   // 121,296

__device__ __forceinline__ float h16f(uint32_t bits) {
    union { uint16_t u; _Float16 h; } c; c.u = (uint16_t)bits; return (float)c.h;
}
__device__ __forceinline__ uint16_t f2h_bits(float f) {
    union { _Float16 h; uint16_t u; } c; c.h = (_Float16)f; return c.u;
}
__device__ __forceinline__ uint32_t pkrtz(float x, float y) {
    typedef __fp16 h2 __attribute__((ext_vector_type(2)));
    union { h2 h; uint32_t u; } c; c.h = __builtin_amdgcn_cvt_pkrtz(x, y); return c.u;
}
#define SWZ(v, pat) __uint_as_float(__builtin_amdgcn_ds_swizzle(__float_as_uint(v), pat))

__global__ void init_ws_kernel(uint32_t* __restrict__ ctr, uint32_t* __restrict__ ht0) {
    size_t i = (size_t)blockIdx.x * blockDim.x + threadIdx.x;
    if (i < CTR_ELEMS) ctr[i] = 0;
    if (i < HT_HALF / 2) ht0[i] = 0;   // zero h buffer 0 (h_{-1} = 0), u32 view
}

__global__ void build_ell_kernel(const float* __restrict__ Whh, const float* __restrict__ mask,
                                 const float* __restrict__ Wih,
                                 uint32_t* __restrict__ ent, uint32_t* __restrict__ cnt) {
    int d = blockIdx.x * blockDim.x + threadIdx.x;
    if (d >= HH) return;
    int area = (d >= AH) ? 1 : 0;
    const float* mrow = mask + (size_t)d * HH + (size_t)area * AH;
    const float* wrow = Whh + (size_t)d * HH + (size_t)area * AH;
    uint32_t* erow = ent + (size_t)d * KMAX;
    uint32_t n = 0;
    for (int c = 0; c < AH; ++c) {
        float m = mrow[c];
        if (m != 0.0f) {
            float w = wrow[c] * m;
            if (n < KMAX) erow[n] = ((uint32_t)c << 16) | (uint32_t)f2h_bits(w);
            n++;
        }
    }
    for (int i = 0; i < NI; ++i) {      // fold input projection as extra "columns"
        if (n < KMAX) erow[n] = ((uint32_t)(COLS + i) << 16) | (uint32_t)f2h_bits(Wih[(size_t)d * NI + i]);
        n++;
    }
    cnt[d] = (n < KMAX) ? n : KMAX;
}

__global__ void xt_kernel(const float* __restrict__ x, float* __restrict__ xT) {
    int i = blockIdx.x * blockDim.x + threadIdx.x;  // [t][i][b]
    if (i >= NT * NI * NBATCH) return;
    int b = i % NBATCH;
    int rest = i / NBATCH;
    int ii = rest % NI;
    int t = rest / NI;
    xT[i] = x[((size_t)b * NT + t) * NI + ii];
}

__global__ __launch_bounds__(NTHREADS, 4) void rnn_kernel(
    const uint32_t* __restrict__ ent, const uint32_t* __restrict__ cnt,
    const float* __restrict__ xT, uint16_t* __restrict__ hT,
    uint32_t* __restrict__ ctr,
    const float* __restrict__ bih, const float* __restrict__ bhh,
    float* __restrict__ out)
{
    extern __shared__ char smem[];
    uint4*    hlds4 = (uint4*)(smem + OFF_HLDS);     // f16 [COLT][16]
    uint32_t* entl  = (uint32_t*)(smem + OFF_ENTL);  // [NRW][KPAD]
    float*    hnew  = (float*)(smem + OFF_HNEW);     // [NRW][17]
    float*    biasl = (float*)(smem + OFF_BIAS);
    uint32_t* cntl  = (uint32_t*)(smem + OFF_CNT);
    __shared__ int sG, sRole, sFast;

    const int tid = threadIdx.x;
    uint32_t* xcdcnt = ctr + 2056;
    uint32_t* gbar   = ctr + 2064;

    // ---- placement detection + hand-rolled grid barrier ----
    if (tid == 0) {
        uint32_t xcc;
        asm volatile("s_getreg_b32 %0, hwreg(HW_REG_XCC_ID, 0, 4)" : "=s"(xcc));
        xcc &= 7u;
        uint32_t rank = __hip_atomic_fetch_add(&xcdcnt[xcc], 1u, __ATOMIC_RELAXED,
                                               __HIP_MEMORY_SCOPE_AGENT);
        __hip_atomic_fetch_add(gbar, 1u, __ATOMIC_RELEASE, __HIP_MEMORY_SCOPE_AGENT);
        while (__hip_atomic_load(gbar, __ATOMIC_ACQUIRE, __HIP_MEMORY_SCOPE_AGENT) < (uint32_t)NBLOCKS)
            __builtin_amdgcn_s_sleep(2);
        bool ok = true;
        for (int i = 0; i < 8; ++i)
            ok &= (__hip_atomic_load(&xcdcnt[i], __ATOMIC_RELAXED, __HIP_MEMORY_SCOPE_AGENT) == 32u);
        if (ok) { sG = (int)xcc; sRole = (int)rank; }
        else    { sG = blockIdx.x & 7; sRole = blockIdx.x >> 3; }
        sFast = ok ? 1 : 0;
    }
    __syncthreads();
    const int G = sG, role = sRole, fast = sFast;
    const int a = G >> 2, g = G & 3;
    const int row0 = role * NRW;            // area-local
    const int Rg0  = a * AH + row0;         // global row

    // ---- step-invariant staging ----
    {
        const uint4* esrc = (const uint4*)(ent + (size_t)Rg0 * KMAX);
        for (int i = tid; i < NRW * (KMAX / 4); i += NTHREADS) {
            int r = i / (KMAX / 4), c = i % (KMAX / 4);
            ((uint4*)(entl + r * KPAD))[c] = esrc[i];
        }
        for (int i = tid; i < NRW; i += NTHREADS) {
            biasl[i] = bih[Rg0 + i] + bhh[Rg0 + i];
            cntl[i] = cnt[Rg0 + i];
        }
    }

    const int wv = tid >> 6, lane = tid & 63;
    const int ro = lane >> 4;          // 0..3 row within wave
    const int kq = (lane >> 1) & 7;    // 0..7 k-stripe
    const int o  = lane & 1;           // 0..1 batch octet

    for (int t = 0; t < NT; ++t) {
        // ---- wait for previous step's slab ----
        if (t > 0) {
            if (tid == 0) {
                while (__hip_atomic_load(&ctr[(size_t)t * 8 + G], __ATOMIC_RELAXED,
                                         __HIP_MEMORY_SCOPE_AGENT) < 32u)
                    __builtin_amdgcn_s_sleep(2);
                if (!fast) __threadfence();   // cross-XCD acquire (L2 inv)
            }
            __syncthreads();
            if (fast) asm volatile("buffer_inv sc0" ::: "memory");  // L1-only inv
        }
        // ---- stage h slab (f16 [1920][16] = 61440 B) ----
        {
            const uint4* src = (const uint4*)(hT + (size_t)(t & 1) * HT_HALF + (size_t)G * AH * NB);
            for (int i = tid; i < 3840; i += NTHREADS) hlds4[i] = src[i];
        }
        // ---- stage x_t tail (cols 1920..1937) ----
        if (tid < 144) {
            int i = tid >> 3, bp = tid & 7;
            const float* xs = xT + ((size_t)t * NI + i) * NBATCH + g * NB + bp * 2;
            float2 xv = *(const float2*)xs;
            ((uint32_t*)hlds4)[(size_t)(COLS + i) * 8 + bp] = pkrtz(xv.x, xv.y);
        }
        __syncthreads();

        // ---- compute ----
        if (wv < 15) {
            const int r = wv * 4 + ro;
            const int n = (int)cntl[r];
            const uint32_t* ep = entl + r * KPAD;
            float a0 = 0.f, a1 = 0.f, a2 = 0.f, a3 = 0.f, a4 = 0.f, a5 = 0.f, a6 = 0.f, a7 = 0.f;
            #pragma unroll 2
            for (int k = kq; k < n; k += 8) {
                uint32_t e = ep[k];
                uint4 hv = hlds4[(e >> 16) * 2 + o];
                float wf = h16f(e);
                a0 = fmaf(wf, h16f(hv.x), a0);
                a1 = fmaf(wf, h16f(hv.x >> 16), a1);
                a2 = fmaf(wf, h16f(hv.y), a2);
                a3 = fmaf(wf, h16f(hv.y >> 16), a3);
                a4 = fmaf(wf, h16f(hv.z), a4);
                a5 = fmaf(wf, h16f(hv.z >> 16), a5);
                a6 = fmaf(wf, h16f(hv.w), a6);
                a7 = fmaf(wf, h16f(hv.w >> 16), a7);
            }
            // reduce over kq (lane bits 3:1)
            a0 += SWZ(a0, 0x081F); a1 += SWZ(a1, 0x081F); a2 += SWZ(a2, 0x081F); a3 += SWZ(a3, 0x081F);
            a4 += SWZ(a4, 0x081F); a5 += SWZ(a5, 0x081F); a6 += SWZ(a6, 0x081F); a7 += SWZ(a7, 0x081F);
            a0 += SWZ(a0, 0x101F); a1 += SWZ(a1, 0x101F); a2 += SWZ(a2, 0x101F); a3 += SWZ(a3, 0x101F);
            a4 += SWZ(a4, 0x101F); a5 += SWZ(a5, 0x101F); a6 += SWZ(a6, 0x101F); a7 += SWZ(a7, 0x101F);
            a0 += SWZ(a0, 0x201F); a1 += SWZ(a1, 0x201F); a2 += SWZ(a2, 0x201F); a3 += SWZ(a3, 0x201F);
            a4 += SWZ(a4, 0x201F); a5 += SWZ(a5, 0x201F); a6 += SWZ(a6, 0x201F); a7 += SWZ(a7, 0x201F);
            if (kq == 0) {
                float bv = biasl[r];
                float* hp = hnew + r * 17 + o * 8;
                hp[0] = fmaxf(a0 + bv, 0.f); hp[1] = fmaxf(a1 + bv, 0.f);
                hp[2] = fmaxf(a2 + bv, 0.f); hp[3] = fmaxf(a3 + bv, 0.f);
                hp[4] = fmaxf(a4 + bv, 0.f); hp[5] = fmaxf(a5 + bv, 0.f);
                hp[6] = fmaxf(a6 + bv, 0.f); hp[7] = fmaxf(a7 + bv, 0.f);
            }
        }
        __syncthreads();

        // ---- publish next slab (f16) ----
        if (tid < 480) {
            int rr = tid >> 3, bp = tid & 7;
            uint16_t* dst = hT + (size_t)((t + 1) & 1) * HT_HALF + (size_t)G * AH * NB
                            + (size_t)(row0 + rr) * NB;
            ((uint32_t*)dst)[bp] = pkrtz(hnew[rr * 17 + bp * 2], hnew[rr * 17 + bp * 2 + 1]);
        }
        if (!fast) {
            __syncthreads();
            if (tid == 0) { __threadfence(); }   // cross-XCD release (L2 wb)
        } else {
            asm volatile("s_waitcnt vmcnt(0)" ::: "memory");
            __syncthreads();
        }
        if (tid == 0)
            __hip_atomic_fetch_add(&ctr[(size_t)(t + 1) * 8 + G], 1u, __ATOMIC_RELAXED,
                                   __HIP_MEMORY_SCOPE_AGENT);
        // ---- output tile (off critical path) ----
        {
            int bb = tid >> 6, d = tid & 63;
            if (d < NRW)
                out[(((size_t)(g * NB + bb)) * NT + t) * HH + (size_t)a * AH + row0 + d]
                    = hnew[d * 17 + bb];
        }
    }
}

extern "C" void kernel_launch(void* const* d_in, const int* in_sizes, int n_in,
                              void* d_out, int out_size, void* d_ws, size_t ws_size,
                              hipStream_t stream)
{
    const float* x    = (const float*)d_in[0];
    const float* Wih  = (const float*)d_in[1];
    const float* bih  = (const float*)d_in[2];
    const float* Whh  = (const float*)d_in[3];
    const float* bhh  = (const float*)d_in[4];
    const float* mask = (const float*)d_in[5];
    float* out = (float*)d_out;

    char* ws = (char*)d_ws;
    uint32_t* ent = (uint32_t*)(ws);
    uint32_t* cnt = (uint32_t*)(ws + ENT_BYTES);
    float*    xT  = (float*)(ws + ENT_BYTES + CNT_BYTES);
    uint16_t* hT  = (uint16_t*)(ws + ENT_BYTES + CNT_BYTES + XT_BYTES);
    uint32_t* ctr = (uint32_t*)(ws + ENT_BYTES + CNT_BYTES + XT_BYTES + HT_BYTES);

    init_ws_kernel<<<512, 256, 0, stream>>>(ctr, (uint32_t*)hT);
    build_ell_kernel<<<(HH + 255) / 256, 256, 0, stream>>>(Whh, mask, Wih, ent, cnt);
    xt_kernel<<<(NT * NI * NBATCH + 255) / 256, 256, 0, stream>>>(x, xT);

    hipFuncSetAttribute((const void*)rnn_kernel,
                        hipFuncAttributeMaxDynamicSharedMemorySize, SMEM_BYTES);

    void* args[] = {(void*)&ent, (void*)&cnt, (void*)&xT, (void*)&hT, (void*)&ctr,
                    (void*)&bih, (void*)&bhh, (void*)&out};
    hipLaunchCooperativeKernel((const void*)rnn_kernel, dim3(NBLOCKS), dim3(NTHREADS),
                               args, SMEM_BYTES, stream);
}

// Round 4
// 3069.048 us; speedup vs baseline: 7.1048x; 1.5767x over previous
//
#include <hip/hip_runtime.h>
#include <stdint.h>
#include <stddef.h>

#define HH 3840
#define AH 1920
#define NI 18
#define NT 256
#define NBATCH 64
#define KMAX 224      // ELL capacity per row, incl. 18 input entries
#define KPAD 228      // LDS row stride (bank spread: 228 % 32 = 4)
#define NRW 60        // rows per block
#define NB 16         // batches per group
#define COLS 1920
#define COLT 1938     // 1920 h cols + 18 x cols
#define NBLOCKS 256
#define NTHREADS 1024

// ---- ws layout (bytes) ----
#define ENT_BYTES ((size_t)HH * KMAX * 4)            // 3,440,640
#define CNT_BYTES ((size_t)HH * 4)                   // 15,360
#define XT_BYTES  ((size_t)NT * NI * NBATCH * 4)     // 1,179,648
#define HT_HALF   ((size_t)8 * AH * NB)              // u16 elems per buffer = 245,760
#define HT_BYTES  (2 * HT_HALF * 2)                  // 983,040 (double buffered)
#define FLAG_ELEMS ((size_t)8 * 32 * 32)             // u32: slot per (G,role), 128B padded = 8192
#define PC_ELEMS  16                                 // xcdcnt[8] + gbar @ [8]

// ---- LDS layout (bytes) ----
#define OFF_HLDS  0
#define HLDS_B    (COLT * 32)            // 62,016  f16 [COLT][16]
#define OFF_ENTL  (OFF_HLDS + HLDS_B)    // 62,016
#define ENTL_B    (NRW * KPAD * 4)       // 54,720
#define OFF_HNEW  (OFF_ENTL + ENTL_B)    // 116,736
#define HNEW_B    (NRW * 17 * 4)         // 4,080
#define OFF_BIAS  (OFF_HNEW + HNEW_B)    // 120,816
#define OFF_CNT   (OFF_BIAS + NRW * 4)   // 121,056
#define SMEM_BYTES (OFF_CNT + NRW * 4)   // 121,296

__device__ __forceinline__ float h16f(uint32_t bits) {
    union { uint16_t u; _Float16 h; } c; c.u = (uint16_t)bits; return (float)c.h;
}
__device__ __forceinline__ uint16_t f2h_bits(float f) {
    union { _Float16 h; uint16_t u; } c; c.h = (_Float16)f; return c.u;
}
__device__ __forceinline__ uint32_t pkrtz(float x, float y) {
    typedef __fp16 h2 __attribute__((ext_vector_type(2)));
    union { h2 h; uint32_t u; } c; c.h = __builtin_amdgcn_cvt_pkrtz(x, y); return c.u;
}
#define SWZ(v, pat) __uint_as_float(__builtin_amdgcn_ds_swizzle(__float_as_uint(v), pat))

__global__ void init_ws_kernel(uint32_t* __restrict__ flg, uint32_t* __restrict__ ht0) {
    size_t i = (size_t)blockIdx.x * blockDim.x + threadIdx.x;
    if (i < FLAG_ELEMS + PC_ELEMS) flg[i] = 0;
    if (i < HT_HALF / 2) ht0[i] = 0;   // zero h buffer 0 (h_{-1} = 0), u32 view
}

// one wave per destination row: ballot+popc packing of nonzero mask entries
__global__ void build_ell_kernel(const float* __restrict__ Whh, const float* __restrict__ mask,
                                 const float* __restrict__ Wih,
                                 uint32_t* __restrict__ ent, uint32_t* __restrict__ cnt) {
    int gw = (int)((blockIdx.x * blockDim.x + threadIdx.x) >> 6);
    int lane = threadIdx.x & 63;
    if (gw >= HH) return;
    const int d = gw;
    const int area = (d >= AH) ? 1 : 0;
    const float* mrow = mask + (size_t)d * HH + (size_t)area * AH;
    const float* wrow = Whh + (size_t)d * HH + (size_t)area * AH;
    uint32_t* erow = ent + (size_t)d * KMAX;
    uint32_t base = 0;
    for (int c0 = 0; c0 < AH; c0 += 64) {
        int c = c0 + lane;
        float m = mrow[c];
        bool pred = (m != 0.0f);
        uint64_t mk = __ballot(pred);
        if (pred) {
            uint32_t pos = base + (uint32_t)__popcll(mk & ((1ull << lane) - 1ull));
            if (pos < KMAX) erow[pos] = ((uint32_t)c << 16) | (uint32_t)f2h_bits(wrow[c] * m);
        }
        base += (uint32_t)__popcll(mk);
    }
    if (lane < NI) {   // fold input projection as extra "columns"
        uint32_t pos = base + (uint32_t)lane;
        if (pos < KMAX)
            erow[pos] = ((uint32_t)(COLS + lane) << 16) | (uint32_t)f2h_bits(Wih[(size_t)d * NI + lane]);
    }
    base += NI;
    if (lane == 0) cnt[d] = (base < KMAX) ? base : KMAX;
}

__global__ void xt_kernel(const float* __restrict__ x, float* __restrict__ xT) {
    int i = blockIdx.x * blockDim.x + threadIdx.x;  // [t][i][b]
    if (i >= NT * NI * NBATCH) return;
    int b = i % NBATCH;
    int rest = i / NBATCH;
    int ii = rest % NI;
    int t = rest / NI;
    xT[i] = x[((size_t)b * NT + t) * NI + ii];
}

__global__ __launch_bounds__(NTHREADS, 4) void rnn_kernel(
    const uint32_t* __restrict__ ent, const uint32_t* __restrict__ cnt,
    const float* __restrict__ xT, uint16_t* __restrict__ hT,
    uint32_t* __restrict__ flg,
    const float* __restrict__ bih, const float* __restrict__ bhh,
    float* __restrict__ out)
{
    extern __shared__ char smem[];
    uint4*    hlds4 = (uint4*)(smem + OFF_HLDS);     // f16 [COLT][16]
    uint32_t* entl  = (uint32_t*)(smem + OFF_ENTL);  // [NRW][KPAD]
    float*    hnew  = (float*)(smem + OFF_HNEW);     // [NRW][17]
    float*    biasl = (float*)(smem + OFF_BIAS);
    uint32_t* cntl  = (uint32_t*)(smem + OFF_CNT);
    __shared__ int sG, sRole, sFast;

    const int tid = threadIdx.x;
    uint32_t* xcdcnt = flg + FLAG_ELEMS;
    uint32_t* gbar   = flg + FLAG_ELEMS + 8;

    // ---- placement detection + hand-rolled grid barrier ----
    if (tid == 0) {
        uint32_t xcc;
        asm volatile("s_getreg_b32 %0, hwreg(HW_REG_XCC_ID, 0, 4)" : "=s"(xcc));
        xcc &= 7u;
        uint32_t rank = __hip_atomic_fetch_add(&xcdcnt[xcc], 1u, __ATOMIC_RELAXED,
                                               __HIP_MEMORY_SCOPE_AGENT);
        __hip_atomic_fetch_add(gbar, 1u, __ATOMIC_RELEASE, __HIP_MEMORY_SCOPE_AGENT);
        while (__hip_atomic_load(gbar, __ATOMIC_ACQUIRE, __HIP_MEMORY_SCOPE_AGENT) < (uint32_t)NBLOCKS)
            __builtin_amdgcn_s_sleep(2);
        bool ok = true;
        for (int i = 0; i < 8; ++i)
            ok &= (__hip_atomic_load(&xcdcnt[i], __ATOMIC_RELAXED, __HIP_MEMORY_SCOPE_AGENT) == 32u);
        if (ok) { sG = (int)xcc; sRole = (int)rank; }
        else    { sG = blockIdx.x & 7; sRole = blockIdx.x >> 3; }
        sFast = ok ? 1 : 0;
    }
    __syncthreads();
    const int G = sG, role = sRole, fast = sFast;
    const int a = G >> 2, g = G & 3;
    const int row0 = role * NRW;            // area-local
    const int Rg0  = a * AH + row0;         // global row
    const size_t mySlot = ((size_t)G * 32 + role) * 32;

    // ---- step-invariant staging ----
    {
        const uint4* esrc = (const uint4*)(ent + (size_t)Rg0 * KMAX);
        for (int i = tid; i < NRW * (KMAX / 4); i += NTHREADS) {
            int r = i / (KMAX / 4), c = i % (KMAX / 4);
            ((uint4*)(entl + r * KPAD))[c] = esrc[i];
        }
        for (int i = tid; i < NRW; i += NTHREADS) {
            biasl[i] = bih[Rg0 + i] + bhh[Rg0 + i];
            cntl[i] = cnt[Rg0 + i];
        }
    }

    const int wv = tid >> 6, lane = tid & 63;
    const int ro = lane >> 4;          // 0..3 row within wave
    const int kq = (lane >> 1) & 7;    // 0..7 k-stripe
    const int o  = lane & 1;           // 0..1 batch octet

    for (int t = 0; t < NT; ++t) {
        // ---- wait for previous step's slab: 32 lanes poll 32 per-block flags ----
        if (t > 0) {
            if (tid < 32) {
                const uint32_t* sl = flg + ((size_t)G * 32 + tid) * 32;
                uint32_t v;
                do {
                    v = __hip_atomic_load(sl, __ATOMIC_RELAXED, __HIP_MEMORY_SCOPE_AGENT);
                } while (v < (uint32_t)t);
            }
            __syncthreads();
            if (fast) {
                asm volatile("buffer_inv sc0" ::: "memory");  // L1-only inv
            } else {
                if (tid == 0) __threadfence();                 // cross-XCD acquire
                __syncthreads();
            }
        }
        // ---- stage h slab (f16 [1920][16] = 61440 B) ----
        {
            const uint4* src = (const uint4*)(hT + (size_t)(t & 1) * HT_HALF + (size_t)G * AH * NB);
            for (int i = tid; i < 3840; i += NTHREADS) hlds4[i] = src[i];
        }
        // ---- stage x_t tail (cols 1920..1937) ----
        if (tid < 144) {
            int i = tid >> 3, bp = tid & 7;
            const float* xs = xT + ((size_t)t * NI + i) * NBATCH + g * NB + bp * 2;
            float2 xv = *(const float2*)xs;
            ((uint32_t*)hlds4)[(size_t)(COLS + i) * 8 + bp] = pkrtz(xv.x, xv.y);
        }
        __syncthreads();

        // ---- compute ----
        if (wv < 15) {
            const int r = wv * 4 + ro;
            const int n = (int)cntl[r];
            const uint32_t* ep = entl + r * KPAD;
            float a0 = 0.f, a1 = 0.f, a2 = 0.f, a3 = 0.f, a4 = 0.f, a5 = 0.f, a6 = 0.f, a7 = 0.f;
            #pragma unroll 2
            for (int k = kq; k < n; k += 8) {
                uint32_t e = ep[k];
                uint4 hv = hlds4[(e >> 16) * 2 + o];
                float wf = h16f(e);
                a0 = fmaf(wf, h16f(hv.x), a0);
                a1 = fmaf(wf, h16f(hv.x >> 16), a1);
                a2 = fmaf(wf, h16f(hv.y), a2);
                a3 = fmaf(wf, h16f(hv.y >> 16), a3);
                a4 = fmaf(wf, h16f(hv.z), a4);
                a5 = fmaf(wf, h16f(hv.z >> 16), a5);
                a6 = fmaf(wf, h16f(hv.w), a6);
                a7 = fmaf(wf, h16f(hv.w >> 16), a7);
            }
            // reduce over kq (lane bits 3:1)
            a0 += SWZ(a0, 0x081F); a1 += SWZ(a1, 0x081F); a2 += SWZ(a2, 0x081F); a3 += SWZ(a3, 0x081F);
            a4 += SWZ(a4, 0x081F); a5 += SWZ(a5, 0x081F); a6 += SWZ(a6, 0x081F); a7 += SWZ(a7, 0x081F);
            a0 += SWZ(a0, 0x101F); a1 += SWZ(a1, 0x101F); a2 += SWZ(a2, 0x101F); a3 += SWZ(a3, 0x101F);
            a4 += SWZ(a4, 0x101F); a5 += SWZ(a5, 0x101F); a6 += SWZ(a6, 0x101F); a7 += SWZ(a7, 0x101F);
            a0 += SWZ(a0, 0x201F); a1 += SWZ(a1, 0x201F); a2 += SWZ(a2, 0x201F); a3 += SWZ(a3, 0x201F);
            a4 += SWZ(a4, 0x201F); a5 += SWZ(a5, 0x201F); a6 += SWZ(a6, 0x201F); a7 += SWZ(a7, 0x201F);
            if (kq == 0) {
                float bv = biasl[r];
                float* hp = hnew + r * 17 + o * 8;
                hp[0] = fmaxf(a0 + bv, 0.f); hp[1] = fmaxf(a1 + bv, 0.f);
                hp[2] = fmaxf(a2 + bv, 0.f); hp[3] = fmaxf(a3 + bv, 0.f);
                hp[4] = fmaxf(a4 + bv, 0.f); hp[5] = fmaxf(a5 + bv, 0.f);
                hp[6] = fmaxf(a6 + bv, 0.f); hp[7] = fmaxf(a7 + bv, 0.f);
            }
        }
        __syncthreads();

        // ---- publish next slab (f16) ----
        if (tid < 480) {
            int rr = tid >> 3, bp = tid & 7;
            uint16_t* dst = hT + (size_t)((t + 1) & 1) * HT_HALF + (size_t)G * AH * NB
                            + (size_t)(row0 + rr) * NB;
            ((uint32_t*)dst)[bp] = pkrtz(hnew[rr * 17 + bp * 2], hnew[rr * 17 + bp * 2 + 1]);
        }
        if (fast) {
            asm volatile("s_waitcnt vmcnt(0)" ::: "memory");
            __syncthreads();
            if (tid == 0)
                __hip_atomic_store(flg + mySlot, (uint32_t)(t + 1), __ATOMIC_RELAXED,
                                   __HIP_MEMORY_SCOPE_AGENT);
        } else {
            __syncthreads();
            if (tid == 0) {
                __threadfence();   // cross-XCD release
                __hip_atomic_store(flg + mySlot, (uint32_t)(t + 1), __ATOMIC_RELEASE,
                                   __HIP_MEMORY_SCOPE_AGENT);
            }
        }
        // ---- output tile (off critical path) ----
        {
            int bb = tid >> 6, d = tid & 63;
            if (d < NRW)
                out[(((size_t)(g * NB + bb)) * NT + t) * HH + (size_t)a * AH + row0 + d]
                    = hnew[d * 17 + bb];
        }
    }
}

extern "C" void kernel_launch(void* const* d_in, const int* in_sizes, int n_in,
                              void* d_out, int out_size, void* d_ws, size_t ws_size,
                              hipStream_t stream)
{
    const float* x    = (const float*)d_in[0];
    const float* Wih  = (const float*)d_in[1];
    const float* bih  = (const float*)d_in[2];
    const float* Whh  = (const float*)d_in[3];
    const float* bhh  = (const float*)d_in[4];
    const float* mask = (const float*)d_in[5];
    float* out = (float*)d_out;

    char* ws = (char*)d_ws;
    uint32_t* ent = (uint32_t*)(ws);
    uint32_t* cnt = (uint32_t*)(ws + ENT_BYTES);
    float*    xT  = (float*)(ws + ENT_BYTES + CNT_BYTES);
    uint16_t* hT  = (uint16_t*)(ws + ENT_BYTES + CNT_BYTES + XT_BYTES);
    uint32_t* flg = (uint32_t*)(ws + ENT_BYTES + CNT_BYTES + XT_BYTES + HT_BYTES);

    init_ws_kernel<<<512, 256, 0, stream>>>(flg, (uint32_t*)hT);
    build_ell_kernel<<<(HH * 64 + 255) / 256, 256, 0, stream>>>(Whh, mask, Wih, ent, cnt);
    xt_kernel<<<(NT * NI * NBATCH + 255) / 256, 256, 0, stream>>>(x, xT);

    hipFuncSetAttribute((const void*)rnn_kernel,
                        hipFuncAttributeMaxDynamicSharedMemorySize, SMEM_BYTES);

    void* args[] = {(void*)&ent, (void*)&cnt, (void*)&xT, (void*)&hT, (void*)&flg,
                    (void*)&bih, (void*)&bhh, (void*)&out};
    hipLaunchCooperativeKernel((const void*)rnn_kernel, dim3(NBLOCKS), dim3(NTHREADS),
                               args, SMEM_BYTES, stream);
}

// Round 6
// 2868.102 us; speedup vs baseline: 7.6026x; 1.0701x over previous
//
#include <hip/hip_runtime.h>
#include <stdint.h>
#include <stddef.h>

#define HH 3840
#define AH 1920
#define NI 18
#define NT 256
#define NBATCH 64
#define KMAX 224      // ELL capacity per row, incl. 18 input entries
#define JSLOT 28      // KMAX/8 per-lane entry slots
#define NRW 120       // rows per block
#define NB 8          // batches per group
#define NGROUP 16     // 2 areas * 8 batch-tiles
#define NBLK_G 16     // blocks per group
#define NBLOCKS 256
#define NTHREADS 1024
#define COLS 1920
#define COLT 1938     // 1920 h cols + 18 x cols
#define HNEW_PAD 9

// ---- ws layout (bytes) ----
#define ENT_BYTES ((size_t)HH * KMAX * 4)            // 3,440,640
#define CNT_BYTES ((size_t)HH * 4)                   // 15,360
#define XT2_BYTES ((size_t)NT * NI * NBATCH * 2)     // 589,824 (f16)
#define HT_HALF   ((size_t)NGROUP * AH * NB)         // u16 elems per buffer = 245,760
#define HT_BYTES  (2 * HT_HALF * 2)                  // 983,040 (double buffered)
#define FLAG_ELEMS ((size_t)NGROUP * NBLK_G * 32)    // 8192 (128B-padded slots)
#define PC_ELEMS  16                                 // xcdcnt[8] + gbar @ [8]

// ---- LDS (dynamic) ----
#define OFF_SLAB  0
#define SLAB_B    (COLT * 16)            // 31,008
#define OFF_HNEW  SLAB_B                 // 31,008
#define HNEW_B    (NRW * HNEW_PAD * 4)   // 4,320
#define SMEM_USED (OFF_HNEW + HNEW_B)    // 35,328
#define SMEM_ALLOC 83968                 // force 1 block/CU

#define AS1 __attribute__((address_space(1)))
#define AS3 __attribute__((address_space(3)))

__device__ __forceinline__ float lo16(uint32_t u) {
    union { uint16_t q; _Float16 h; } c; c.q = (uint16_t)u; return (float)c.h;
}
__device__ __forceinline__ float hi16(uint32_t u) { return lo16(u >> 16); }
__device__ __forceinline__ uint16_t f2h_bits(float f) {
    union { _Float16 h; uint16_t u; } c; c.h = (_Float16)f; return c.u;
}
__device__ __forceinline__ uint32_t pkrtz(float x, float y) {
    typedef __fp16 h2 __attribute__((ext_vector_type(2)));
    union { h2 h; uint32_t u; } c; c.h = __builtin_amdgcn_cvt_pkrtz(x, y); return c.u;
}
__device__ __forceinline__ void gll16(const void* g, void* l) {
    __builtin_amdgcn_global_load_lds((const AS1 uint32_t*)g, (AS3 uint32_t*)l, 16, 0, 0);
}
#define SWZ(v, pat) __uint_as_float(__builtin_amdgcn_ds_swizzle(__float_as_uint(v), pat))

__global__ void init_ws_kernel(uint32_t* __restrict__ flg, uint32_t* __restrict__ ht0) {
    size_t i = (size_t)blockIdx.x * blockDim.x + threadIdx.x;
    if (i < FLAG_ELEMS + PC_ELEMS) flg[i] = 0;
    if (i < HT_HALF / 2) ht0[i] = 0;   // zero h buffer 0 (h_{-1} = 0), u32 view
}

// one wave per destination row: ballot+popc packing of nonzero mask entries
__global__ void build_ell_kernel(const float* __restrict__ Whh, const float* __restrict__ mask,
                                 const float* __restrict__ Wih,
                                 uint32_t* __restrict__ ent, uint32_t* __restrict__ cnt) {
    int gw = (int)((blockIdx.x * blockDim.x + threadIdx.x) >> 6);
    int lane = threadIdx.x & 63;
    if (gw >= HH) return;
    const int d = gw;
    const int area = (d >= AH) ? 1 : 0;
    const float* mrow = mask + (size_t)d * HH + (size_t)area * AH;
    const float* wrow = Whh + (size_t)d * HH + (size_t)area * AH;
    uint32_t* erow = ent + (size_t)d * KMAX;
    uint32_t base = 0;
    for (int c0 = 0; c0 < AH; c0 += 64) {
        int c = c0 + lane;
        float m = mrow[c];
        bool pred = (m != 0.0f);
        uint64_t mk = __ballot(pred);
        if (pred) {
            uint32_t pos = base + (uint32_t)__popcll(mk & ((1ull << lane) - 1ull));
            if (pos < KMAX) erow[pos] = ((uint32_t)c << 16) | (uint32_t)f2h_bits(wrow[c] * m);
        }
        base += (uint32_t)__popcll(mk);
    }
    if (lane < NI) {   // fold input projection as extra "columns"
        uint32_t pos = base + (uint32_t)lane;
        if (pos < KMAX)
            erow[pos] = ((uint32_t)(COLS + lane) << 16) | (uint32_t)f2h_bits(Wih[(size_t)d * NI + lane]);
    }
    base += NI;
    if (lane == 0) cnt[d] = (base < KMAX) ? base : KMAX;
}

__global__ void xt_kernel(const float* __restrict__ x, uint16_t* __restrict__ xT2) {
    int i = blockIdx.x * blockDim.x + threadIdx.x;  // [t][i][b]
    if (i >= NT * NI * NBATCH) return;
    int b = i % NBATCH;
    int rest = i / NBATCH;
    int ii = rest % NI;
    int t = rest / NI;
    xT2[i] = f2h_bits(x[((size_t)b * NT + t) * NI + ii]);
}

__global__ __launch_bounds__(NTHREADS, 4) void rnn_kernel(
    const uint32_t* __restrict__ ent, const uint32_t* __restrict__ cnt,
    const uint16_t* __restrict__ xT2, uint16_t* __restrict__ hT,
    uint32_t* __restrict__ flg,
    const float* __restrict__ bih, const float* __restrict__ bhh,
    float* __restrict__ out)
{
    extern __shared__ char smem[];
    uint4* slab = (uint4*)(smem + OFF_SLAB);     // f16 [COLT][8]
    float* hnew = (float*)(smem + OFF_HNEW);     // [NRW][9]
    __shared__ int sG, sRole, sFast;

    const int tid = threadIdx.x;
    uint32_t* xcdcnt = flg + FLAG_ELEMS;
    uint32_t* gbar   = flg + FLAG_ELEMS + 8;

    // ---- placement detection + hand-rolled grid barrier (round-4 proven) ----
    if (tid == 0) {
        uint32_t xcc;
        asm volatile("s_getreg_b32 %0, hwreg(HW_REG_XCC_ID, 0, 4)" : "=s"(xcc));
        xcc &= 7u;
        uint32_t rank = __hip_atomic_fetch_add(&xcdcnt[xcc], 1u, __ATOMIC_RELAXED,
                                               __HIP_MEMORY_SCOPE_AGENT);
        __hip_atomic_fetch_add(gbar, 1u, __ATOMIC_RELEASE, __HIP_MEMORY_SCOPE_AGENT);
        while (__hip_atomic_load(gbar, __ATOMIC_ACQUIRE, __HIP_MEMORY_SCOPE_AGENT) < (uint32_t)NBLOCKS)
            __builtin_amdgcn_s_sleep(2);
        bool ok = true;
        for (int i = 0; i < 8; ++i)
            ok &= (__hip_atomic_load(&xcdcnt[i], __ATOMIC_RELAXED, __HIP_MEMORY_SCOPE_AGENT) == 32u);
        if (ok) { sG = (int)(xcc * 2 + (rank >> 4)); sRole = (int)(rank & 15); }
        else    { sG = blockIdx.x & 15; sRole = blockIdx.x >> 4; }
        sFast = ok ? 1 : 0;
    }
    __syncthreads();
    const int G = sG, role = sRole, fast = sFast;
    const int a = G >> 3, g = G & 7;
    const int row0 = role * NRW;                 // area-local
    const size_t mySlot = ((size_t)G * NBLK_G + role) * 32;

    const int wv = tid >> 6, lane = tid & 63;
    const int ro = lane >> 3;          // 0..7 row within wave
    const int kq = lane & 7;           // 0..7 k-stripe
    const int r  = wv * 8 + ro;        // block-local row (valid for wv < 15)

    // ---- hoist step-invariant entries into VGPRs ----
    float wj[JSLOT];
    int   aj[JSLOT];
    float biasr = 0.f;
    int wm = 0;
    if (wv < 15) {
        const int gRow = a * AH + row0 + r;
        const int n = (int)cnt[gRow];
        biasr = bih[gRow] + bhh[gRow];
        int jmax = (n > kq) ? ((n - kq + 7) >> 3) : 0;
        const uint32_t* ep = ent + (size_t)gRow * KMAX;
        #pragma unroll
        for (int j = 0; j < JSLOT; ++j) {
            uint32_t e = (j < jmax) ? ep[kq + 8 * j] : 0u;
            aj[j] = (int)((e >> 16) * 16);           // byte addr of slab[col]
            wj[j] = (j < jmax) ? lo16(e) : 0.0f;
        }
        wm = jmax;
        #pragma unroll
        for (int s = 1; s < 64; s <<= 1) {
            int ov = __shfl_xor(wm, s, 64);
            wm = (ov > wm) ? ov : wm;                // wave-uniform trip count
        }
    }

    for (int t = 0; t < NT; ++t) {
        // ---- x tail prefetch (step-known, no dependency) ----
        if (tid >= 896 && tid < 896 + NI) {
            int i = tid - 896;                       // wave 14, lanes 0..17
            gll16(xT2 + ((size_t)t * NI + i) * NBATCH + g * NB, &slab[COLS + i]);
        }
        // ---- wait for previous step's slab: every wave polls the 16 flags ----
        if (t > 0) {
            if (lane < NBLK_G) {
                const uint32_t* sl = flg + ((size_t)G * NBLK_G + lane) * 32;
                while (__hip_atomic_load(sl, __ATOMIC_RELAXED, __HIP_MEMORY_SCOPE_AGENT)
                       < (uint32_t)t)
                    __builtin_amdgcn_s_sleep(1);
            }
            if (fast) {
                asm volatile("buffer_inv sc0" ::: "memory");  // L1-only inv
            } else {
                __threadfence();                               // cross-XCD acquire
            }
        }
        // ---- stage h slab via global_load_lds (16B per lane) ----
        {
            const uint4* src4 = (const uint4*)(hT + (size_t)(t & 1) * HT_HALF
                                               + (size_t)G * AH * NB);
            gll16(src4 + tid, &slab[tid]);                      // cols 0..1023
            if (tid < 896)
                gll16(src4 + 1024 + tid, &slab[1024 + tid]);    // cols 1024..1919
            asm volatile("s_waitcnt vmcnt(0)" ::: "memory");
        }
        __syncthreads();

        // ---- compute ----
        if (wv < 15) {
            float c0 = 0.f, c1 = 0.f, c2 = 0.f, c3 = 0.f, c4 = 0.f, c5 = 0.f, c6 = 0.f, c7 = 0.f;
            #pragma unroll
            for (int j = 0; j < JSLOT; ++j) {
                if (j >= wm) break;
                const uint4 hv = *(const uint4*)((const char*)slab + aj[j]);
                const float wf = wj[j];
                c0 = fmaf(wf, lo16(hv.x), c0);
                c1 = fmaf(wf, hi16(hv.x), c1);
                c2 = fmaf(wf, lo16(hv.y), c2);
                c3 = fmaf(wf, hi16(hv.y), c3);
                c4 = fmaf(wf, lo16(hv.z), c4);
                c5 = fmaf(wf, hi16(hv.z), c5);
                c6 = fmaf(wf, lo16(hv.w), c6);
                c7 = fmaf(wf, hi16(hv.w), c7);
            }
            // reduce across kq (lane bits 0..2)
            c0 += SWZ(c0, 0x041F); c1 += SWZ(c1, 0x041F); c2 += SWZ(c2, 0x041F); c3 += SWZ(c3, 0x041F);
            c4 += SWZ(c4, 0x041F); c5 += SWZ(c5, 0x041F); c6 += SWZ(c6, 0x041F); c7 += SWZ(c7, 0x041F);
            c0 += SWZ(c0, 0x081F); c1 += SWZ(c1, 0x081F); c2 += SWZ(c2, 0x081F); c3 += SWZ(c3, 0x081F);
            c4 += SWZ(c4, 0x081F); c5 += SWZ(c5, 0x081F); c6 += SWZ(c6, 0x081F); c7 += SWZ(c7, 0x081F);
            c0 += SWZ(c0, 0x101F); c1 += SWZ(c1, 0x101F); c2 += SWZ(c2, 0x101F); c3 += SWZ(c3, 0x101F);
            c4 += SWZ(c4, 0x101F); c5 += SWZ(c5, 0x101F); c6 += SWZ(c6, 0x101F); c7 += SWZ(c7, 0x101F);
            if (kq == 0) {
                float h0 = fmaxf(c0 + biasr, 0.f), h1 = fmaxf(c1 + biasr, 0.f);
                float h2 = fmaxf(c2 + biasr, 0.f), h3 = fmaxf(c3 + biasr, 0.f);
                float h4 = fmaxf(c4 + biasr, 0.f), h5 = fmaxf(c5 + biasr, 0.f);
                float h6 = fmaxf(c6 + biasr, 0.f), h7 = fmaxf(c7 + biasr, 0.f);
                uint4 pk;
                pk.x = pkrtz(h0, h1); pk.y = pkrtz(h2, h3);
                pk.z = pkrtz(h4, h5); pk.w = pkrtz(h6, h7);
                uint16_t* dst = hT + (size_t)((t + 1) & 1) * HT_HALF
                                + ((size_t)G * AH + row0 + r) * NB;
                *(uint4*)dst = pk;                       // direct publish (plain store -> L2)
                float* hp = hnew + r * HNEW_PAD;
                hp[0] = h0; hp[1] = h1; hp[2] = h2; hp[3] = h3;
                hp[4] = h4; hp[5] = h5; hp[6] = h6; hp[7] = h7;
            }
        }
        asm volatile("s_waitcnt vmcnt(0)" ::: "memory");  // publish committed
        __syncthreads();                                   // hnew complete

        if (fast) {
            if (tid == 0)
                __hip_atomic_store(flg + mySlot, (uint32_t)(t + 1), __ATOMIC_RELAXED,
                                   __HIP_MEMORY_SCOPE_AGENT);
        } else if (tid == 0) {
            __threadfence();                               // cross-XCD release
            __hip_atomic_store(flg + mySlot, (uint32_t)(t + 1), __ATOMIC_RELEASE,
                               __HIP_MEMORY_SCOPE_AGENT);
        }
        // ---- output tile (off critical path) ----
        {
            int bb = tid >> 7, d = tid & 127;
            if (d < NRW)
                out[(((size_t)(g * NB + bb)) * NT + t) * HH + (size_t)a * AH + row0 + d]
                    = hnew[d * HNEW_PAD + bb];
        }
    }
}

extern "C" void kernel_launch(void* const* d_in, const int* in_sizes, int n_in,
                              void* d_out, int out_size, void* d_ws, size_t ws_size,
                              hipStream_t stream)
{
    const float* x    = (const float*)d_in[0];
    const float* Wih  = (const float*)d_in[1];
    const float* bih  = (const float*)d_in[2];
    const float* Whh  = (const float*)d_in[3];
    const float* bhh  = (const float*)d_in[4];
    const float* mask = (const float*)d_in[5];
    float* out = (float*)d_out;

    char* ws = (char*)d_ws;
    uint32_t* ent = (uint32_t*)(ws);
    uint32_t* cnt = (uint32_t*)(ws + ENT_BYTES);
    uint16_t* xT2 = (uint16_t*)(ws + ENT_BYTES + CNT_BYTES);
    uint16_t* hT  = (uint16_t*)(ws + ENT_BYTES + CNT_BYTES + XT2_BYTES);
    uint32_t* flg = (uint32_t*)(ws + ENT_BYTES + CNT_BYTES + XT2_BYTES + HT_BYTES);

    init_ws_kernel<<<512, 256, 0, stream>>>(flg, (uint32_t*)hT);
    build_ell_kernel<<<(HH * 64 + 255) / 256, 256, 0, stream>>>(Whh, mask, Wih, ent, cnt);
    xt_kernel<<<(NT * NI * NBATCH + 255) / 256, 256, 0, stream>>>(x, xT2);

    hipFuncSetAttribute((const void*)rnn_kernel,
                        hipFuncAttributeMaxDynamicSharedMemorySize, SMEM_ALLOC);

    void* args[] = {(void*)&ent, (void*)&cnt, (void*)&xT2, (void*)&hT, (void*)&flg,
                    (void*)&bih, (void*)&bhh, (void*)&out};
    hipLaunchCooperativeKernel((const void*)rnn_kernel, dim3(NBLOCKS), dim3(NTHREADS),
                               args, SMEM_ALLOC, stream);
}

// Round 7
// 2800.340 us; speedup vs baseline: 7.7866x; 1.0242x over previous
//
#include <hip/hip_runtime.h>
#include <stdint.h>
#include <stddef.h>

#define HH 3840
#define AH 1920
#define NI 18
#define NT 256
#define NBATCH 64
#define KMAX 224      // ELL capacity per row, incl. 18 input entries
#define JSLOT 28      // KMAX/8 per-lane entry slots
#define NRW 120       // rows per block
#define NB 8          // batches per group
#define NGROUP 16     // 2 areas * 8 batch-tiles
#define NBLK_G 16     // blocks per group
#define NBLOCKS 256
#define NTHREADS 1024
#define COLS 1920
#define COLT 1938     // 1920 h cols + 18 x cols
#define HNEW_PAD 9

// ---- ws layout (bytes) ----
#define ENT_BYTES ((size_t)HH * KMAX * 4)            // 3,440,640
#define CNT_BYTES ((size_t)HH * 4)                   // 15,360
#define XT2_BYTES ((size_t)NT * NI * NBATCH * 2)     // 589,824 (f16)
#define HT_HALF   ((size_t)NGROUP * AH * NB)         // u16 elems per buffer = 245,760
#define HT_BYTES  (2 * HT_HALF * 2)                  // 983,040 (double buffered)
#define FLAG_ELEMS ((size_t)NGROUP * NBLK_G * 32)    // 8192 (128B-padded slots)
#define PC_ELEMS  16                                 // xcdcnt[8] + gbar @ [8]

// ---- LDS (dynamic) ----
#define OFF_SLAB  0
#define SLAB_B    (COLT * 16)            // 31,008
#define OFF_HNEW  SLAB_B                 // 31,008
#define HNEW_B    (NRW * HNEW_PAD * 4)   // 4,320
#define SMEM_USED (OFF_HNEW + HNEW_B)    // 35,328
#define SMEM_ALLOC 83968                 // force 1 block/CU

#define AS1 __attribute__((address_space(1)))
#define AS3 __attribute__((address_space(3)))

__device__ __forceinline__ float lo16(uint32_t u) {
    union { uint16_t q; _Float16 h; } c; c.q = (uint16_t)u; return (float)c.h;
}
__device__ __forceinline__ float hi16(uint32_t u) { return lo16(u >> 16); }
__device__ __forceinline__ uint16_t f2h_bits(float f) {
    union { _Float16 h; uint16_t u; } c; c.h = (_Float16)f; return c.u;
}
__device__ __forceinline__ uint32_t pkrtz(float x, float y) {
    typedef __fp16 h2 __attribute__((ext_vector_type(2)));
    union { h2 h; uint32_t u; } c; c.h = __builtin_amdgcn_cvt_pkrtz(x, y); return c.u;
}
__device__ __forceinline__ void gll16(const void* g, void* l) {
    __builtin_amdgcn_global_load_lds((const AS1 uint32_t*)g, (AS3 uint32_t*)l, 16, 0, 0);
}
#define SWZ(v, pat) __uint_as_float(__builtin_amdgcn_ds_swizzle(__float_as_uint(v), pat))
// DPP add: quad_perm cross-lane sums on the VALU pipe (no lgkm latency)
#define DPA(c, ctrl) c += __uint_as_float(__builtin_amdgcn_mov_dpp(__float_as_uint(c), ctrl, 0xF, 0xF, true))

__global__ void init_ws_kernel(uint32_t* __restrict__ flg, uint32_t* __restrict__ ht0) {
    size_t i = (size_t)blockIdx.x * blockDim.x + threadIdx.x;
    if (i < FLAG_ELEMS + PC_ELEMS) flg[i] = 0;
    if (i < HT_HALF / 2) ht0[i] = 0;   // zero h buffer 0 (h_{-1} = 0), u32 view
}

// one wave per destination row: ballot+popc packing of nonzero mask entries
__global__ void build_ell_kernel(const float* __restrict__ Whh, const float* __restrict__ mask,
                                 const float* __restrict__ Wih,
                                 uint32_t* __restrict__ ent, uint32_t* __restrict__ cnt) {
    int gw = (int)((blockIdx.x * blockDim.x + threadIdx.x) >> 6);
    int lane = threadIdx.x & 63;
    if (gw >= HH) return;
    const int d = gw;
    const int area = (d >= AH) ? 1 : 0;
    const float* mrow = mask + (size_t)d * HH + (size_t)area * AH;
    const float* wrow = Whh + (size_t)d * HH + (size_t)area * AH;
    uint32_t* erow = ent + (size_t)d * KMAX;
    uint32_t base = 0;
    for (int c0 = 0; c0 < AH; c0 += 64) {
        int c = c0 + lane;
        float m = mrow[c];
        bool pred = (m != 0.0f);
        uint64_t mk = __ballot(pred);
        if (pred) {
            uint32_t pos = base + (uint32_t)__popcll(mk & ((1ull << lane) - 1ull));
            if (pos < KMAX) erow[pos] = ((uint32_t)c << 16) | (uint32_t)f2h_bits(wrow[c] * m);
        }
        base += (uint32_t)__popcll(mk);
    }
    if (lane < NI) {   // fold input projection as extra "columns"
        uint32_t pos = base + (uint32_t)lane;
        if (pos < KMAX)
            erow[pos] = ((uint32_t)(COLS + lane) << 16) | (uint32_t)f2h_bits(Wih[(size_t)d * NI + lane]);
    }
    base += NI;
    if (lane == 0) cnt[d] = (base < KMAX) ? base : KMAX;
}

__global__ void xt_kernel(const float* __restrict__ x, uint16_t* __restrict__ xT2) {
    int i = blockIdx.x * blockDim.x + threadIdx.x;  // [t][i][b]
    if (i >= NT * NI * NBATCH) return;
    int b = i % NBATCH;
    int rest = i / NBATCH;
    int ii = rest % NI;
    int t = rest / NI;
    xT2[i] = f2h_bits(x[((size_t)b * NT + t) * NI + ii]);
}

__global__ __launch_bounds__(NTHREADS, 4) void rnn_kernel(
    const uint32_t* __restrict__ ent, const uint32_t* __restrict__ cnt,
    const uint16_t* __restrict__ xT2, uint16_t* __restrict__ hT,
    uint32_t* __restrict__ flg,
    const float* __restrict__ bih, const float* __restrict__ bhh,
    float* __restrict__ out)
{
    extern __shared__ char smem[];
    uint4* slab = (uint4*)(smem + OFF_SLAB);     // f16 [COLT][8]
    float* hnew = (float*)(smem + OFF_HNEW);     // [NRW][9]
    __shared__ int sG, sRole, sFast;

    const int tid = threadIdx.x;
    uint32_t* xcdcnt = flg + FLAG_ELEMS;
    uint32_t* gbar   = flg + FLAG_ELEMS + 8;

    // ---- placement detection + hand-rolled grid barrier (round-4/6 proven) ----
    if (tid == 0) {
        uint32_t xcc;
        asm volatile("s_getreg_b32 %0, hwreg(HW_REG_XCC_ID, 0, 4)" : "=s"(xcc));
        xcc &= 7u;
        uint32_t rank = __hip_atomic_fetch_add(&xcdcnt[xcc], 1u, __ATOMIC_RELAXED,
                                               __HIP_MEMORY_SCOPE_AGENT);
        __hip_atomic_fetch_add(gbar, 1u, __ATOMIC_RELEASE, __HIP_MEMORY_SCOPE_AGENT);
        while (__hip_atomic_load(gbar, __ATOMIC_ACQUIRE, __HIP_MEMORY_SCOPE_AGENT) < (uint32_t)NBLOCKS)
            __builtin_amdgcn_s_sleep(2);
        bool ok = true;
        for (int i = 0; i < 8; ++i)
            ok &= (__hip_atomic_load(&xcdcnt[i], __ATOMIC_RELAXED, __HIP_MEMORY_SCOPE_AGENT) == 32u);
        if (ok) { sG = (int)(xcc * 2 + (rank >> 4)); sRole = (int)(rank & 15); }
        else    { sG = blockIdx.x & 15; sRole = blockIdx.x >> 4; }
        sFast = ok ? 1 : 0;
    }
    __syncthreads();
    const int G = sG, role = sRole, fast = sFast;
    const int a = G >> 3, g = G & 7;
    const int row0 = role * NRW;                 // area-local
    const size_t mySlot = ((size_t)G * NBLK_G + role) * 32;

    const int wv = tid >> 6, lane = tid & 63;
    const int ro = lane >> 3;          // 0..7 row within wave
    const int kq = lane & 7;           // 0..7 k-stripe
    const int r  = wv * 8 + ro;        // block-local row (valid for wv < 15)

    // ---- hoist step-invariant entries into VGPRs ----
    float wj[JSLOT];
    int   aj[JSLOT];
    float biasr = 0.f;
    int wm = 0;
    if (wv < 15) {
        const int gRow = a * AH + row0 + r;
        const int n = (int)cnt[gRow];
        biasr = bih[gRow] + bhh[gRow];
        int jmax = (n > kq) ? ((n - kq + 7) >> 3) : 0;
        const uint32_t* ep = ent + (size_t)gRow * KMAX;
        #pragma unroll
        for (int j = 0; j < JSLOT; ++j) {
            uint32_t e = (j < jmax) ? ep[kq + 8 * j] : 0u;
            aj[j] = (int)((e >> 16) * 16);           // byte addr of slab[col]
            wj[j] = (j < jmax) ? lo16(e) : 0.0f;
        }
        wm = jmax;
        #pragma unroll
        for (int s = 1; s < 64; s <<= 1) {
            int ov = __shfl_xor(wm, s, 64);
            wm = (ov > wm) ? ov : wm;                // wave-uniform trip count
        }
    }

    for (int t = 0; t < NT; ++t) {
        // ---- x tail prefetch (step-known, no dependency) ----
        if (tid >= 896 && tid < 896 + NI) {
            int i = tid - 896;                       // wave 14, lanes 0..17
            gll16(xT2 + ((size_t)t * NI + i) * NBATCH + g * NB, &slab[COLS + i]);
        }
        // ---- wait for previous step: wave 0 polls the 16 group flags ----
        if (t > 0) {
            if (wv == 0 && lane < NBLK_G) {
                const uint32_t* sl = flg + ((size_t)G * NBLK_G + lane) * 32;
                if (fast) {
                    // L2-local poll: inv L1 each iter, plain load hits local L2
                    uint32_t v; int guard = 0;
                    do {
                        asm volatile("buffer_inv sc0" ::: "memory");
                        v = *(volatile const uint32_t*)sl;
                    } while (v < (uint32_t)t && ++guard < (1 << 20));
                } else {
                    while (__hip_atomic_load(sl, __ATOMIC_RELAXED, __HIP_MEMORY_SCOPE_AGENT)
                           < (uint32_t)t)
                        __builtin_amdgcn_s_sleep(1);
                }
            }
            __syncthreads();
            if (!fast) __threadfence();              // cross-XCD acquire
        }
        // ---- stage h slab via global_load_lds (16B per lane) ----
        {
            asm volatile("buffer_inv sc0" ::: "memory");        // drop stale L1
            const uint4* src4 = (const uint4*)(hT + (size_t)(t & 1) * HT_HALF
                                               + (size_t)G * AH * NB);
            gll16(src4 + tid, &slab[tid]);                      // cols 0..1023
            if (tid < 896)
                gll16(src4 + 1024 + tid, &slab[1024 + tid]);    // cols 1024..1919
            asm volatile("s_waitcnt vmcnt(0)" ::: "memory");
        }
        __syncthreads();

        // ---- compute ----
        if (wv < 15) {
            float c0 = 0.f, c1 = 0.f, c2 = 0.f, c3 = 0.f, c4 = 0.f, c5 = 0.f, c6 = 0.f, c7 = 0.f;
            #pragma unroll
            for (int j = 0; j < JSLOT; ++j) {
                if (j >= wm) break;
                const uint4 hv = *(const uint4*)((const char*)slab + aj[j]);
                const float wf = wj[j];
                c0 = fmaf(wf, lo16(hv.x), c0);
                c1 = fmaf(wf, hi16(hv.x), c1);
                c2 = fmaf(wf, lo16(hv.y), c2);
                c3 = fmaf(wf, hi16(hv.y), c3);
                c4 = fmaf(wf, lo16(hv.z), c4);
                c5 = fmaf(wf, hi16(hv.z), c5);
                c6 = fmaf(wf, lo16(hv.w), c6);
                c7 = fmaf(wf, hi16(hv.w), c7);
            }
            // reduce across kq: xor4 via ds_swizzle, xor2/xor1 via DPP quad_perm
            c0 += SWZ(c0, 0x101F); c1 += SWZ(c1, 0x101F); c2 += SWZ(c2, 0x101F); c3 += SWZ(c3, 0x101F);
            c4 += SWZ(c4, 0x101F); c5 += SWZ(c5, 0x101F); c6 += SWZ(c6, 0x101F); c7 += SWZ(c7, 0x101F);
            DPA(c0, 0x4E); DPA(c1, 0x4E); DPA(c2, 0x4E); DPA(c3, 0x4E);
            DPA(c4, 0x4E); DPA(c5, 0x4E); DPA(c6, 0x4E); DPA(c7, 0x4E);
            DPA(c0, 0xB1); DPA(c1, 0xB1); DPA(c2, 0xB1); DPA(c3, 0xB1);
            DPA(c4, 0xB1); DPA(c5, 0xB1); DPA(c6, 0xB1); DPA(c7, 0xB1);
            if (kq == 0) {
                float h0 = fmaxf(c0 + biasr, 0.f), h1 = fmaxf(c1 + biasr, 0.f);
                float h2 = fmaxf(c2 + biasr, 0.f), h3 = fmaxf(c3 + biasr, 0.f);
                float h4 = fmaxf(c4 + biasr, 0.f), h5 = fmaxf(c5 + biasr, 0.f);
                float h6 = fmaxf(c6 + biasr, 0.f), h7 = fmaxf(c7 + biasr, 0.f);
                uint4 pk;
                pk.x = pkrtz(h0, h1); pk.y = pkrtz(h2, h3);
                pk.z = pkrtz(h4, h5); pk.w = pkrtz(h6, h7);
                uint16_t* dst = hT + (size_t)((t + 1) & 1) * HT_HALF
                                + ((size_t)G * AH + row0 + r) * NB;
                *(uint4*)dst = pk;                       // direct publish (plain store -> L2)
                float* hp = hnew + r * HNEW_PAD;
                hp[0] = h0; hp[1] = h1; hp[2] = h2; hp[3] = h3;
                hp[4] = h4; hp[5] = h5; hp[6] = h6; hp[7] = h7;
            }
        }
        asm volatile("s_waitcnt vmcnt(0)" ::: "memory");  // publish committed to L2
        __syncthreads();                                   // hnew complete

        if (tid == 0) {
            if (fast) {
                *(volatile uint32_t*)(flg + mySlot) = (uint32_t)(t + 1);  // plain store -> local L2
            } else {
                __threadfence();                           // cross-XCD release
                __hip_atomic_store(flg + mySlot, (uint32_t)(t + 1), __ATOMIC_RELEASE,
                                   __HIP_MEMORY_SCOPE_AGENT);
            }
        }
        // ---- output tile (off critical path) ----
        {
            int bb = tid >> 7, d = tid & 127;
            if (d < NRW)
                out[(((size_t)(g * NB + bb)) * NT + t) * HH + (size_t)a * AH + row0 + d]
                    = hnew[d * HNEW_PAD + bb];
        }
    }
}

extern "C" void kernel_launch(void* const* d_in, const int* in_sizes, int n_in,
                              void* d_out, int out_size, void* d_ws, size_t ws_size,
                              hipStream_t stream)
{
    const float* x    = (const float*)d_in[0];
    const float* Wih  = (const float*)d_in[1];
    const float* bih  = (const float*)d_in[2];
    const float* Whh  = (const float*)d_in[3];
    const float* bhh  = (const float*)d_in[4];
    const float* mask = (const float*)d_in[5];
    float* out = (float*)d_out;

    char* ws = (char*)d_ws;
    uint32_t* ent = (uint32_t*)(ws);
    uint32_t* cnt = (uint32_t*)(ws + ENT_BYTES);
    uint16_t* xT2 = (uint16_t*)(ws + ENT_BYTES + CNT_BYTES);
    uint16_t* hT  = (uint16_t*)(ws + ENT_BYTES + CNT_BYTES + XT2_BYTES);
    uint32_t* flg = (uint32_t*)(ws + ENT_BYTES + CNT_BYTES + XT2_BYTES + HT_BYTES);

    init_ws_kernel<<<512, 256, 0, stream>>>(flg, (uint32_t*)hT);
    build_ell_kernel<<<(HH * 64 + 255) / 256, 256, 0, stream>>>(Whh, mask, Wih, ent, cnt);
    xt_kernel<<<(NT * NI * NBATCH + 255) / 256, 256, 0, stream>>>(x, xT2);

    hipFuncSetAttribute((const void*)rnn_kernel,
                        hipFuncAttributeMaxDynamicSharedMemorySize, SMEM_ALLOC);

    void* args[] = {(void*)&ent, (void*)&cnt, (void*)&xT2, (void*)&hT, (void*)&flg,
                    (void*)&bih, (void*)&bhh, (void*)&out};
    hipLaunchCooperativeKernel((const void*)rnn_kernel, dim3(NBLOCKS), dim3(NTHREADS),
                               args, SMEM_ALLOC, stream);
}

// Round 8
// 2792.573 us; speedup vs baseline: 7.8082x; 1.0028x over previous
//
#include <hip/hip_runtime.h>
#include <stdint.h>
#include <stddef.h>

#define HH 3840
#define AH 1920
#define NI 18
#define NT 256
#define NBATCH 64
#define KMAX 224      // ELL capacity per row, incl. 18 input entries
#define JSLOT 28      // KMAX/8 per-lane entry slots
#define NRW 120       // rows per block
#define NB 8          // batches per group
#define NGROUP 16     // 2 areas * 8 batch-tiles
#define NBLK_G 16     // blocks per group
#define NBLOCKS 256
#define NTHREADS 1024
#define COLS 1920
#define COLT 1938     // 1920 h cols + 18 x cols
#define HNEW_PAD 9

// ---- ws layout (bytes) ----
#define ENT_BYTES ((size_t)HH * KMAX * 4)            // 3,440,640
#define CNT_BYTES ((size_t)HH * 4)                   // 15,360
#define XT2_BYTES ((size_t)NT * NI * NBATCH * 2)     // 589,824 (f16)
#define HT_HALF   ((size_t)NGROUP * AH * NB)         // u16 elems per buffer = 245,760
#define HT_BYTES  (2 * HT_HALF * 2)                  // 983,040 (double buffered)
#define FLAG_ELEMS ((size_t)NGROUP * NBLK_G * 32)    // 8192 (128B-padded slots)
#define PC_ELEMS  16                                 // xcdcnt[8] + gbar @ [8]

// ---- LDS (dynamic) ----
#define OFF_SLAB  0
#define SLAB_B    (COLT * 16)            // 31,008
#define OFF_HNEW  SLAB_B                 // 31,008
#define HNEW_B    (NRW * HNEW_PAD * 4)   // 4,320
#define SMEM_USED (OFF_HNEW + HNEW_B)    // 35,328
#define SMEM_ALLOC 83968                 // force 1 block/CU

#define AS1 __attribute__((address_space(1)))
#define AS3 __attribute__((address_space(3)))

__device__ __forceinline__ float lo16(uint32_t u) {
    union { uint16_t q; _Float16 h; } c; c.q = (uint16_t)u; return (float)c.h;
}
__device__ __forceinline__ float hi16(uint32_t u) { return lo16(u >> 16); }
__device__ __forceinline__ uint16_t f2h_bits(float f) {
    union { _Float16 h; uint16_t u; } c; c.h = (_Float16)f; return c.u;
}
__device__ __forceinline__ uint32_t pkrtz(float x, float y) {
    typedef __fp16 h2 __attribute__((ext_vector_type(2)));
    union { h2 h; uint32_t u; } c; c.h = __builtin_amdgcn_cvt_pkrtz(x, y); return c.u;
}
__device__ __forceinline__ void gll16(const void* g, void* l) {
    __builtin_amdgcn_global_load_lds((const AS1 uint32_t*)g, (AS3 uint32_t*)l, 16, 0, 0);
}
#define SWZ(v, pat) __uint_as_float(__builtin_amdgcn_ds_swizzle(__float_as_uint(v), pat))
// DPP add: quad_perm cross-lane sums on the VALU pipe (no lgkm latency)
#define DPA(c, ctrl) c += __uint_as_float(__builtin_amdgcn_mov_dpp(__float_as_uint(c), ctrl, 0xF, 0xF, true))

__global__ void init_ws_kernel(uint32_t* __restrict__ flg, uint32_t* __restrict__ ht0) {
    size_t i = (size_t)blockIdx.x * blockDim.x + threadIdx.x;
    if (i < FLAG_ELEMS + PC_ELEMS) flg[i] = 0;
    if (i < HT_HALF / 2) ht0[i] = 0;   // zero h buffer 0 (h_{-1} = 0), u32 view
}

// one wave per destination row: ballot+popc packing of nonzero mask entries
__global__ void build_ell_kernel(const float* __restrict__ Whh, const float* __restrict__ mask,
                                 const float* __restrict__ Wih,
                                 uint32_t* __restrict__ ent, uint32_t* __restrict__ cnt) {
    int gw = (int)((blockIdx.x * blockDim.x + threadIdx.x) >> 6);
    int lane = threadIdx.x & 63;
    if (gw >= HH) return;
    const int d = gw;
    const int area = (d >= AH) ? 1 : 0;
    const float* mrow = mask + (size_t)d * HH + (size_t)area * AH;
    const float* wrow = Whh + (size_t)d * HH + (size_t)area * AH;
    uint32_t* erow = ent + (size_t)d * KMAX;
    uint32_t base = 0;
    for (int c0 = 0; c0 < AH; c0 += 64) {
        int c = c0 + lane;
        float m = mrow[c];
        bool pred = (m != 0.0f);
        uint64_t mk = __ballot(pred);
        if (pred) {
            uint32_t pos = base + (uint32_t)__popcll(mk & ((1ull << lane) - 1ull));
            if (pos < KMAX) erow[pos] = ((uint32_t)c << 16) | (uint32_t)f2h_bits(wrow[c] * m);
        }
        base += (uint32_t)__popcll(mk);
    }
    if (lane < NI) {   // fold input projection as extra "columns"
        uint32_t pos = base + (uint32_t)lane;
        if (pos < KMAX)
            erow[pos] = ((uint32_t)(COLS + lane) << 16) | (uint32_t)f2h_bits(Wih[(size_t)d * NI + lane]);
    }
    base += NI;
    if (lane == 0) cnt[d] = (base < KMAX) ? base : KMAX;
}

__global__ void xt_kernel(const float* __restrict__ x, uint16_t* __restrict__ xT2) {
    int i = blockIdx.x * blockDim.x + threadIdx.x;  // [t][i][b]
    if (i >= NT * NI * NBATCH) return;
    int b = i % NBATCH;
    int rest = i / NBATCH;
    int ii = rest % NI;
    int t = rest / NI;
    xT2[i] = f2h_bits(x[((size_t)b * NT + t) * NI + ii]);
}

__global__ __launch_bounds__(NTHREADS, 4) void rnn_kernel(
    const uint32_t* __restrict__ ent, const uint32_t* __restrict__ cnt,
    const uint16_t* __restrict__ xT2, uint16_t* __restrict__ hT,
    uint32_t* __restrict__ flg,
    const float* __restrict__ bih, const float* __restrict__ bhh,
    float* __restrict__ out)
{
    extern __shared__ char smem[];
    uint4* slab = (uint4*)(smem + OFF_SLAB);     // f16 [COLT][8]
    float* hnew = (float*)(smem + OFF_HNEW);     // [NRW][9]
    __shared__ int sG, sRole, sFast;

    const int tid = threadIdx.x;
    uint32_t* xcdcnt = flg + FLAG_ELEMS;
    uint32_t* gbar   = flg + FLAG_ELEMS + 8;

    // ---- placement detection + hand-rolled grid barrier (round-4/6 proven) ----
    if (tid == 0) {
        uint32_t xcc;
        asm volatile("s_getreg_b32 %0, hwreg(HW_REG_XCC_ID, 0, 4)" : "=s"(xcc));
        xcc &= 7u;
        uint32_t rank = __hip_atomic_fetch_add(&xcdcnt[xcc], 1u, __ATOMIC_RELAXED,
                                               __HIP_MEMORY_SCOPE_AGENT);
        __hip_atomic_fetch_add(gbar, 1u, __ATOMIC_RELEASE, __HIP_MEMORY_SCOPE_AGENT);
        while (__hip_atomic_load(gbar, __ATOMIC_ACQUIRE, __HIP_MEMORY_SCOPE_AGENT) < (uint32_t)NBLOCKS)
            __builtin_amdgcn_s_sleep(2);
        bool ok = true;
        for (int i = 0; i < 8; ++i)
            ok &= (__hip_atomic_load(&xcdcnt[i], __ATOMIC_RELAXED, __HIP_MEMORY_SCOPE_AGENT) == 32u);
        if (ok) { sG = (int)(xcc * 2 + (rank >> 4)); sRole = (int)(rank & 15); }
        else    { sG = blockIdx.x & 15; sRole = blockIdx.x >> 4; }
        sFast = ok ? 1 : 0;
    }
    __syncthreads();
    const int G = sG, role = sRole, fast = sFast;
    const int a = G >> 3, g = G & 7;
    const int row0 = role * NRW;                 // area-local
    const size_t mySlot = ((size_t)G * NBLK_G + role) * 32;

    const int wv = tid >> 6, lane = tid & 63;
    const int ro = lane >> 3;          // 0..7 row within wave
    const int kq = lane & 7;           // 0..7 k-stripe
    const int r  = wv * 8 + ro;        // block-local row (valid for wv < 15)

    // ---- hoist step-invariant entries into VGPRs ----
    float wj[JSLOT];
    int   aj[JSLOT];
    float biasr = 0.f;
    int wm = 0;
    if (wv < 15) {
        const int gRow = a * AH + row0 + r;
        const int n = (int)cnt[gRow];
        biasr = bih[gRow] + bhh[gRow];
        int jmax = (n > kq) ? ((n - kq + 7) >> 3) : 0;
        const uint32_t* ep = ent + (size_t)gRow * KMAX;
        #pragma unroll
        for (int j = 0; j < JSLOT; ++j) {
            uint32_t e = (j < jmax) ? ep[kq + 8 * j] : 0u;
            aj[j] = (int)((e >> 16) * 16);           // byte addr of slab[col]
            wj[j] = (j < jmax) ? lo16(e) : 0.0f;
        }
        wm = jmax;
        #pragma unroll
        for (int s = 1; s < 64; s <<= 1) {
            int ov = __shfl_xor(wm, s, 64);
            wm = (ov > wm) ? ov : wm;                // wave-uniform trip count
        }
    }

    for (int t = 0; t < NT; ++t) {
        // ---- x tail prefetch (step-known, const data, no freshness needed) ----
        if (tid >= 896 && tid < 896 + NI) {
            int i = tid - 896;                       // wave 14, lanes 0..17
            gll16(xT2 + ((size_t)t * NI + i) * NBATCH + g * NB, &slab[COLS + i]);
        }
        // ---- wait for previous step: wave 0 polls; ONE L1 inv per block ----
        if (t > 0) {
            if (wv == 0) {
                if (lane < NBLK_G) {
                    const uint32_t* sl = flg + ((size_t)G * NBLK_G + lane) * 32;
                    while (__hip_atomic_load(sl, __ATOMIC_RELAXED, __HIP_MEMORY_SCOPE_AGENT)
                           < (uint32_t)t)
                        __builtin_amdgcn_s_sleep(1);
                }
                if (fast) asm volatile("buffer_inv sc0" ::: "memory");  // single L1 inv
            }
            __syncthreads();
            if (!fast) __threadfence();              // cross-XCD acquire (slow path)
        }
        // ---- stage h slab via global_load_lds (16B per lane); L1 already clean ----
        {
            const uint4* src4 = (const uint4*)(hT + (size_t)(t & 1) * HT_HALF
                                               + (size_t)G * AH * NB);
            gll16(src4 + tid, &slab[tid]);                      // cols 0..1023
            if (tid < 896)
                gll16(src4 + 1024 + tid, &slab[1024 + tid]);    // cols 1024..1919
            asm volatile("s_waitcnt vmcnt(0)" ::: "memory");
        }
        __syncthreads();

        // ---- compute ----
        if (wv < 15) {
            float c0 = 0.f, c1 = 0.f, c2 = 0.f, c3 = 0.f, c4 = 0.f, c5 = 0.f, c6 = 0.f, c7 = 0.f;
            #pragma unroll
            for (int j = 0; j < JSLOT; ++j) {
                if (j >= wm) break;
                const uint4 hv = *(const uint4*)((const char*)slab + aj[j]);
                const float wf = wj[j];
                c0 = fmaf(wf, lo16(hv.x), c0);
                c1 = fmaf(wf, hi16(hv.x), c1);
                c2 = fmaf(wf, lo16(hv.y), c2);
                c3 = fmaf(wf, hi16(hv.y), c3);
                c4 = fmaf(wf, lo16(hv.z), c4);
                c5 = fmaf(wf, hi16(hv.z), c5);
                c6 = fmaf(wf, lo16(hv.w), c6);
                c7 = fmaf(wf, hi16(hv.w), c7);
            }
            // reduce across kq: xor4 via ds_swizzle, xor2/xor1 via DPP quad_perm
            c0 += SWZ(c0, 0x101F); c1 += SWZ(c1, 0x101F); c2 += SWZ(c2, 0x101F); c3 += SWZ(c3, 0x101F);
            c4 += SWZ(c4, 0x101F); c5 += SWZ(c5, 0x101F); c6 += SWZ(c6, 0x101F); c7 += SWZ(c7, 0x101F);
            DPA(c0, 0x4E); DPA(c1, 0x4E); DPA(c2, 0x4E); DPA(c3, 0x4E);
            DPA(c4, 0x4E); DPA(c5, 0x4E); DPA(c6, 0x4E); DPA(c7, 0x4E);
            DPA(c0, 0xB1); DPA(c1, 0xB1); DPA(c2, 0xB1); DPA(c3, 0xB1);
            DPA(c4, 0xB1); DPA(c5, 0xB1); DPA(c6, 0xB1); DPA(c7, 0xB1);
            if (kq == 0) {
                float h0 = fmaxf(c0 + biasr, 0.f), h1 = fmaxf(c1 + biasr, 0.f);
                float h2 = fmaxf(c2 + biasr, 0.f), h3 = fmaxf(c3 + biasr, 0.f);
                float h4 = fmaxf(c4 + biasr, 0.f), h5 = fmaxf(c5 + biasr, 0.f);
                float h6 = fmaxf(c6 + biasr, 0.f), h7 = fmaxf(c7 + biasr, 0.f);
                uint4 pk;
                pk.x = pkrtz(h0, h1); pk.y = pkrtz(h2, h3);
                pk.z = pkrtz(h4, h5); pk.w = pkrtz(h6, h7);
                uint16_t* dst = hT + (size_t)((t + 1) & 1) * HT_HALF
                                + ((size_t)G * AH + row0 + r) * NB;
                *(uint4*)dst = pk;                       // direct publish (plain store -> L2)
                float* hp = hnew + r * HNEW_PAD;
                hp[0] = h0; hp[1] = h1; hp[2] = h2; hp[3] = h3;
                hp[4] = h4; hp[5] = h5; hp[6] = h6; hp[7] = h7;
            }
        }
        asm volatile("s_waitcnt vmcnt(0)" ::: "memory");  // publish committed to L2
        __syncthreads();                                   // hnew complete

        if (tid == 0) {
            if (fast) {
                __hip_atomic_store(flg + mySlot, (uint32_t)(t + 1), __ATOMIC_RELAXED,
                                   __HIP_MEMORY_SCOPE_AGENT);
            } else {
                __threadfence();                           // cross-XCD release
                __hip_atomic_store(flg + mySlot, (uint32_t)(t + 1), __ATOMIC_RELEASE,
                                   __HIP_MEMORY_SCOPE_AGENT);
            }
        }
        // ---- output tile: waves 2..15 only (poller carries no store baggage) ----
        if (tid >= 256) {
            int i = tid - 256;                       // 768 threads for 960 elems
            #pragma unroll
            for (; i < NB * NRW; i += 768) {
                int bb = i / NRW, d = i - bb * NRW;
                out[(((size_t)(g * NB + bb)) * NT + t) * HH + (size_t)a * AH + row0 + d]
                    = hnew[d * HNEW_PAD + bb];
            }
        }
    }
}

extern "C" void kernel_launch(void* const* d_in, const int* in_sizes, int n_in,
                              void* d_out, int out_size, void* d_ws, size_t ws_size,
                              hipStream_t stream)
{
    const float* x    = (const float*)d_in[0];
    const float* Wih  = (const float*)d_in[1];
    const float* bih  = (const float*)d_in[2];
    const float* Whh  = (const float*)d_in[3];
    const float* bhh  = (const float*)d_in[4];
    const float* mask = (const float*)d_in[5];
    float* out = (float*)d_out;

    char* ws = (char*)d_ws;
    uint32_t* ent = (uint32_t*)(ws);
    uint32_t* cnt = (uint32_t*)(ws + ENT_BYTES);
    uint16_t* xT2 = (uint16_t*)(ws + ENT_BYTES + CNT_BYTES);
    uint16_t* hT  = (uint16_t*)(ws + ENT_BYTES + CNT_BYTES + XT2_BYTES);
    uint32_t* flg = (uint32_t*)(ws + ENT_BYTES + CNT_BYTES + XT2_BYTES + HT_BYTES);

    init_ws_kernel<<<512, 256, 0, stream>>>(flg, (uint32_t*)hT);
    build_ell_kernel<<<(HH * 64 + 255) / 256, 256, 0, stream>>>(Whh, mask, Wih, ent, cnt);
    xt_kernel<<<(NT * NI * NBATCH + 255) / 256, 256, 0, stream>>>(x, xT2);

    hipFuncSetAttribute((const void*)rnn_kernel,
                        hipFuncAttributeMaxDynamicSharedMemorySize, SMEM_ALLOC);

    void* args[] = {(void*)&ent, (void*)&cnt, (void*)&xT2, (void*)&hT, (void*)&flg,
                    (void*)&bih, (void*)&bhh, (void*)&out};
    hipLaunchCooperativeKernel((const void*)rnn_kernel, dim3(NBLOCKS), dim3(NTHREADS),
                               args, SMEM_ALLOC, stream);
}

// Round 9
// 1628.353 us; speedup vs baseline: 13.3908x; 1.7150x over previous
//
#include <hip/hip_runtime.h>
#include <stdint.h>
#include <stddef.h>

#define HH 3840
#define AH 1920
#define NI 18
#define NT 256
#define NBATCH 64
#define KMAX 224      // ELL capacity per row, incl. 18 input entries
#define JSLOT 28      // KMAX/8 per-lane entry slots
#define NRW 120       // rows per block
#define NB 8          // batches per group
#define NGROUP 16     // 2 areas * 8 batch-tiles
#define NBLK_G 16     // blocks per group
#define NBLOCKS 256
#define NTHREADS 1024
#define COLS 1920
#define COLT 1938     // 1920 h cols + 18 x cols
#define HNEW_PAD 9

// ---- ws layout (bytes) ----
#define ENT_BYTES ((size_t)HH * KMAX * 4)            // 3,440,640
#define CNT_BYTES ((size_t)HH * 4)                   // 15,360
#define XT2_BYTES ((size_t)NT * NI * NBATCH * 2)     // 589,824 (f16)
#define HT_HALF   ((size_t)NGROUP * AH * NB)         // u16 elems per buffer = 245,760
#define HT_BYTES  (2 * HT_HALF * 2)                  // 983,040 (double buffered)
#define FLAG_ELEMS ((size_t)NGROUP * NBLK_G * 32)    // 8192 (128B-padded slots)
#define PC_ELEMS  16

// ---- LDS (dynamic) ----
#define OFF_SLAB  0
#define SLAB_B    (COLT * 16)            // 31,008
#define OFF_HNEW  SLAB_B                 // 31,008
#define HNEW_B    (2 * NRW * HNEW_PAD * 4)   // 8,640 (double buffered)
#define SMEM_USED (OFF_HNEW + HNEW_B)    // 39,648
#define SMEM_ALLOC 83968                 // force 1 block/CU

#define AS1 __attribute__((address_space(1)))
#define AS3 __attribute__((address_space(3)))

typedef unsigned long long u64;

__device__ __forceinline__ float lo16(uint32_t u) {
    union { uint16_t q; _Float16 h; } c; c.q = (uint16_t)u; return (float)c.h;
}
__device__ __forceinline__ float hi16(uint32_t u) { return lo16(u >> 16); }
__device__ __forceinline__ uint16_t f2h_bits(float f) {
    union { _Float16 h; uint16_t u; } c; c.h = (_Float16)f; return c.u;
}
__device__ __forceinline__ uint32_t pkrtz(float x, float y) {
    typedef __fp16 h2 __attribute__((ext_vector_type(2)));
    union { h2 h; uint32_t u; } c; c.h = __builtin_amdgcn_cvt_pkrtz(x, y); return c.u;
}
__device__ __forceinline__ void gll16(const void* g, void* l) {
    __builtin_amdgcn_global_load_lds((const AS1 uint32_t*)g, (AS3 uint32_t*)l, 16, 0, 0);
}
__device__ __forceinline__ u64 aload(const u64* p) {
    return __hip_atomic_load(p, __ATOMIC_RELAXED, __HIP_MEMORY_SCOPE_AGENT);
}
__device__ __forceinline__ void astore(u64* p, u64 v) {
    __hip_atomic_store(p, v, __ATOMIC_RELAXED, __HIP_MEMORY_SCOPE_AGENT);
}
#define SWZ(v, pat) __uint_as_float(__builtin_amdgcn_ds_swizzle(__float_as_uint(v), pat))
#define DPA(c, ctrl) c += __uint_as_float(__builtin_amdgcn_mov_dpp(__float_as_uint(c), ctrl, 0xF, 0xF, true))

__global__ void init_ws_kernel(uint32_t* __restrict__ flg, uint32_t* __restrict__ ht0) {
    size_t i = (size_t)blockIdx.x * blockDim.x + threadIdx.x;
    if (i < FLAG_ELEMS + PC_ELEMS) flg[i] = 0;
    if (i < HT_HALF / 2) ht0[i] = 0;   // zero h buffer 0 (h_{-1} = 0), u32 view
}

// one wave per destination row: ballot+popc packing of nonzero mask entries
__global__ void build_ell_kernel(const float* __restrict__ Whh, const float* __restrict__ mask,
                                 const float* __restrict__ Wih,
                                 uint32_t* __restrict__ ent, uint32_t* __restrict__ cnt) {
    int gw = (int)((blockIdx.x * blockDim.x + threadIdx.x) >> 6);
    int lane = threadIdx.x & 63;
    if (gw >= HH) return;
    const int d = gw;
    const int area = (d >= AH) ? 1 : 0;
    const float* mrow = mask + (size_t)d * HH + (size_t)area * AH;
    const float* wrow = Whh + (size_t)d * HH + (size_t)area * AH;
    uint32_t* erow = ent + (size_t)d * KMAX;
    uint32_t base = 0;
    for (int c0 = 0; c0 < AH; c0 += 64) {
        int c = c0 + lane;
        float m = mrow[c];
        bool pred = (m != 0.0f);
        uint64_t mk = __ballot(pred);
        if (pred) {
            uint32_t pos = base + (uint32_t)__popcll(mk & ((1ull << lane) - 1ull));
            if (pos < KMAX) erow[pos] = ((uint32_t)c << 16) | (uint32_t)f2h_bits(wrow[c] * m);
        }
        base += (uint32_t)__popcll(mk);
    }
    if (lane < NI) {   // fold input projection as extra "columns"
        uint32_t pos = base + (uint32_t)lane;
        if (pos < KMAX)
            erow[pos] = ((uint32_t)(COLS + lane) << 16) | (uint32_t)f2h_bits(Wih[(size_t)d * NI + lane]);
    }
    base += NI;
    if (lane == 0) cnt[d] = (base < KMAX) ? base : KMAX;
}

__global__ void xt_kernel(const float* __restrict__ x, uint16_t* __restrict__ xT2) {
    int i = blockIdx.x * blockDim.x + threadIdx.x;  // [t][i][b]
    if (i >= NT * NI * NBATCH) return;
    int b = i % NBATCH;
    int rest = i / NBATCH;
    int ii = rest % NI;
    int t = rest / NI;
    xT2[i] = f2h_bits(x[((size_t)b * NT + t) * NI + ii]);
}

__global__ __launch_bounds__(NTHREADS, 4) void rnn_kernel(
    const uint32_t* __restrict__ ent, const uint32_t* __restrict__ cnt,
    const uint16_t* __restrict__ xT2, uint16_t* __restrict__ hT,
    uint32_t* __restrict__ flg,
    const float* __restrict__ bih, const float* __restrict__ bhh,
    float* __restrict__ out)
{
    extern __shared__ char smem[];
    uint4* slab = (uint4*)(smem + OFF_SLAB);     // f16 [COLT][8]
    float* hnew = (float*)(smem + OFF_HNEW);     // [2][NRW][9]

    const int tid = threadIdx.x;
    const int G = blockIdx.x & 15, role = blockIdx.x >> 4;   // placement-independent
    const int a = G >> 3, g = G & 7;
    const int row0 = role * NRW;                 // area-local
    const size_t mySlot = ((size_t)G * NBLK_G + role) * 32;

    const int wv = tid >> 6, lane = tid & 63;
    const int ro = lane >> 3;          // 0..7 row within wave
    const int kq = lane & 7;           // 0..7 k-stripe
    const int r  = wv * 8 + ro;        // block-local row (valid for wv < 15)

    // ---- hoist step-invariant entries into VGPRs ----
    float wj[JSLOT];
    int   aj[JSLOT];
    float biasr = 0.f;
    int wm = 0;
    if (wv < 15) {
        const int gRow = a * AH + row0 + r;
        const int n = (int)cnt[gRow];
        biasr = bih[gRow] + bhh[gRow];
        int jmax = (n > kq) ? ((n - kq + 7) >> 3) : 0;
        const uint32_t* ep = ent + (size_t)gRow * KMAX;
        #pragma unroll
        for (int j = 0; j < JSLOT; ++j) {
            uint32_t e = (j < jmax) ? ep[kq + 8 * j] : 0u;
            aj[j] = (int)((e >> 16) * 16);           // byte addr of slab[col]
            wj[j] = (j < jmax) ? lo16(e) : 0.0f;
        }
        wm = jmax;
        #pragma unroll
        for (int s = 1; s < 64; s <<= 1) {
            int ov = __shfl_xor(wm, s, 64);
            wm = (ov > wm) ? ov : wm;                // wave-uniform trip count
        }
    }

    for (int t = 0; t < NT; ++t) {
        // ---- x tail prefetch (const data, plain path) ----
        if (tid >= 896 && tid < 896 + NI) {
            int i = tid - 896;                       // wave 14, lanes 0..17
            gll16(xT2 + ((size_t)t * NI + i) * NBATCH + g * NB, &slab[COLS + i]);
        }
        // ---- wait for previous step: wave 0 polls 16 flags (agent atomics) ----
        if (t > 0) {
            if (wv == 0 && lane < NBLK_G) {
                const uint32_t* sl = flg + ((size_t)G * NBLK_G + lane) * 32;
                while (__hip_atomic_load(sl, __ATOMIC_RELAXED, __HIP_MEMORY_SCOPE_AGENT)
                       < (uint32_t)t)
                    __builtin_amdgcn_s_sleep(1);
            }
            __syncthreads();
        }
        // ---- stage h slab: coherent u64 loads -> LDS (3840 u64 = 1920 cols) ----
        {
            const u64* src8 = (const u64*)(hT + (size_t)(t & 1) * HT_HALF
                                           + (size_t)G * AH * NB);
            u64* lds8 = (u64*)slab;
            u64 v0 = aload(src8 + tid);
            u64 v1 = aload(src8 + tid + 1024);
            u64 v2 = aload(src8 + tid + 2048);
            u64 v3 = (tid < 768) ? aload(src8 + tid + 3072) : 0;
            lds8[tid] = v0;
            lds8[tid + 1024] = v1;
            lds8[tid + 2048] = v2;
            if (tid < 768) lds8[tid + 3072] = v3;
            asm volatile("s_waitcnt vmcnt(0)" ::: "memory");   // also drains x-tail gll16
        }
        __syncthreads();

        // ---- output tile for step t-1 (reads prev hnew buffer; acks hide under compute) ----
        if (t > 0 && tid >= 256) {
            const float* hp = hnew + ((t - 1) & 1) * NRW * HNEW_PAD;
            for (int i = tid - 256; i < NB * NRW; i += 768) {
                int bb = i / NRW, d = i - bb * NRW;
                out[(((size_t)(g * NB + bb)) * NT + (t - 1)) * HH + (size_t)a * AH + row0 + d]
                    = hp[d * HNEW_PAD + bb];
            }
        }

        // ---- compute ----
        if (wv < 15) {
            float c0 = 0.f, c1 = 0.f, c2 = 0.f, c3 = 0.f, c4 = 0.f, c5 = 0.f, c6 = 0.f, c7 = 0.f;
            #pragma unroll
            for (int j = 0; j < JSLOT; ++j) {
                if (j >= wm) break;
                const uint4 hv = *(const uint4*)((const char*)slab + aj[j]);
                const float wf = wj[j];
                c0 = fmaf(wf, lo16(hv.x), c0);
                c1 = fmaf(wf, hi16(hv.x), c1);
                c2 = fmaf(wf, lo16(hv.y), c2);
                c3 = fmaf(wf, hi16(hv.y), c3);
                c4 = fmaf(wf, lo16(hv.z), c4);
                c5 = fmaf(wf, hi16(hv.z), c5);
                c6 = fmaf(wf, lo16(hv.w), c6);
                c7 = fmaf(wf, hi16(hv.w), c7);
            }
            // reduce across kq: xor4 via ds_swizzle, xor2/xor1 via DPP quad_perm
            c0 += SWZ(c0, 0x101F); c1 += SWZ(c1, 0x101F); c2 += SWZ(c2, 0x101F); c3 += SWZ(c3, 0x101F);
            c4 += SWZ(c4, 0x101F); c5 += SWZ(c5, 0x101F); c6 += SWZ(c6, 0x101F); c7 += SWZ(c7, 0x101F);
            DPA(c0, 0x4E); DPA(c1, 0x4E); DPA(c2, 0x4E); DPA(c3, 0x4E);
            DPA(c4, 0x4E); DPA(c5, 0x4E); DPA(c6, 0x4E); DPA(c7, 0x4E);
            DPA(c0, 0xB1); DPA(c1, 0xB1); DPA(c2, 0xB1); DPA(c3, 0xB1);
            DPA(c4, 0xB1); DPA(c5, 0xB1); DPA(c6, 0xB1); DPA(c7, 0xB1);
            if (kq == 0) {
                float h0 = fmaxf(c0 + biasr, 0.f), h1 = fmaxf(c1 + biasr, 0.f);
                float h2 = fmaxf(c2 + biasr, 0.f), h3 = fmaxf(c3 + biasr, 0.f);
                float h4 = fmaxf(c4 + biasr, 0.f), h5 = fmaxf(c5 + biasr, 0.f);
                float h6 = fmaxf(c6 + biasr, 0.f), h7 = fmaxf(c7 + biasr, 0.f);
                uint32_t p0 = pkrtz(h0, h1), p1 = pkrtz(h2, h3);
                uint32_t p2 = pkrtz(h4, h5), p3 = pkrtz(h6, h7);
                u64* dst8 = (u64*)(hT + (size_t)((t + 1) & 1) * HT_HALF
                                   + ((size_t)G * AH + row0 + r) * NB);
                astore(dst8,     ((u64)p1 << 32) | p0);   // coherent publish (MALL)
                astore(dst8 + 1, ((u64)p3 << 32) | p2);
                float* hp = hnew + (t & 1) * NRW * HNEW_PAD + r * HNEW_PAD;
                hp[0] = h0; hp[1] = h1; hp[2] = h2; hp[3] = h3;
                hp[4] = h4; hp[5] = h5; hp[6] = h6; hp[7] = h7;
            }
        }
        asm volatile("s_waitcnt vmcnt(0)" ::: "memory");  // publish committed
        __syncthreads();                                   // all waves published

        if (tid == 0)
            __hip_atomic_store(flg + mySlot, (uint32_t)(t + 1), __ATOMIC_RELAXED,
                               __HIP_MEMORY_SCOPE_AGENT);
    }
    // ---- epilogue: output for the final step ----
    if (tid >= 256) {
        const float* hp = hnew + ((NT - 1) & 1) * NRW * HNEW_PAD;
        for (int i = tid - 256; i < NB * NRW; i += 768) {
            int bb = i / NRW, d = i - bb * NRW;
            out[(((size_t)(g * NB + bb)) * NT + (NT - 1)) * HH + (size_t)a * AH + row0 + d]
                = hp[d * HNEW_PAD + bb];
        }
    }
}

extern "C" void kernel_launch(void* const* d_in, const int* in_sizes, int n_in,
                              void* d_out, int out_size, void* d_ws, size_t ws_size,
                              hipStream_t stream)
{
    const float* x    = (const float*)d_in[0];
    const float* Wih  = (const float*)d_in[1];
    const float* bih  = (const float*)d_in[2];
    const float* Whh  = (const float*)d_in[3];
    const float* bhh  = (const float*)d_in[4];
    const float* mask = (const float*)d_in[5];
    float* out = (float*)d_out;

    char* ws = (char*)d_ws;
    uint32_t* ent = (uint32_t*)(ws);
    uint32_t* cnt = (uint32_t*)(ws + ENT_BYTES);
    uint16_t* xT2 = (uint16_t*)(ws + ENT_BYTES + CNT_BYTES);
    uint16_t* hT  = (uint16_t*)(ws + ENT_BYTES + CNT_BYTES + XT2_BYTES);
    uint32_t* flg = (uint32_t*)(ws + ENT_BYTES + CNT_BYTES + XT2_BYTES + HT_BYTES);

    init_ws_kernel<<<512, 256, 0, stream>>>(flg, (uint32_t*)hT);
    build_ell_kernel<<<(HH * 64 + 255) / 256, 256, 0, stream>>>(Whh, mask, Wih, ent, cnt);
    xt_kernel<<<(NT * NI * NBATCH + 255) / 256, 256, 0, stream>>>(x, xT2);

    hipFuncSetAttribute((const void*)rnn_kernel,
                        hipFuncAttributeMaxDynamicSharedMemorySize, SMEM_ALLOC);

    void* args[] = {(void*)&ent, (void*)&cnt, (void*)&xT2, (void*)&hT, (void*)&flg,
                    (void*)&bih, (void*)&bhh, (void*)&out};
    hipLaunchCooperativeKernel((const void*)rnn_kernel, dim3(NBLOCKS), dim3(NTHREADS),
                               args, SMEM_ALLOC, stream);
}

// Round 10
// 1138.080 us; speedup vs baseline: 19.1595x; 1.4308x over previous
//
#include <hip/hip_runtime.h>
#include <stdint.h>
#include <stddef.h>

#define HH 3840
#define AH 1920
#define NI 18
#define NT 256
#define NBATCH 64
#define KMAX 224      // ELL capacity per row, incl. 18 input entries
#define JSLOT 28      // KMAX/8 per-lane entry slots
#define NRW 120       // rows per block
#define NB 8          // batches per group
#define NGROUP 16     // 2 areas * 8 batch-tiles
#define NBLK_G 16     // blocks per group
#define NBLOCKS 256
#define NTHREADS 1024
#define COLS 1920
#define COLT 1938     // 1920 h cols + 18 x cols
#define HNEW_PAD 9

// ---- ws layout (bytes) ----
#define ENT_BYTES ((size_t)HH * KMAX * 4)            // 3,440,640
#define CNT_BYTES ((size_t)HH * 4)                   // 15,360
#define XT2_BYTES ((size_t)NT * NI * NBATCH * 2)     // 589,824 (f16)
#define HT_HALF   ((size_t)NGROUP * AH * NB)         // u16 elems per buffer = 245,760
#define HT_BYTES  (2 * HT_HALF * 2)                  // 983,040 (double buffered)
#define FLAG_ELEMS ((size_t)NGROUP * NBLK_G * 32)    // 8192 (128B-padded slots)
#define PC_ELEMS  16

// ---- LDS (dynamic) ----
#define SLAB_B    (COLT * 16)                // 31,008 per buffer
#define OFF_HNEW  (2 * SLAB_B)               // 62,016
#define HNEW_B    (2 * NRW * HNEW_PAD * 4)   // 8,640 (double buffered)
#define SMEM_USED (OFF_HNEW + HNEW_B)        // 70,656
#define SMEM_ALLOC 83968                     // force 1 block/CU

#define AS1 __attribute__((address_space(1)))
#define AS3 __attribute__((address_space(3)))

typedef unsigned long long u64;

__device__ __forceinline__ float lo16(uint32_t u) {
    union { uint16_t q; _Float16 h; } c; c.q = (uint16_t)u; return (float)c.h;
}
__device__ __forceinline__ uint16_t f2h_bits(float f) {
    union { _Float16 h; uint16_t u; } c; c.h = (_Float16)f; return c.u;
}
__device__ __forceinline__ uint32_t pkrtz(float x, float y) {
    typedef __fp16 h2 __attribute__((ext_vector_type(2)));
    union { h2 h; uint32_t u; } c; c.h = __builtin_amdgcn_cvt_pkrtz(x, y); return c.u;
}
__device__ __forceinline__ void gll16(const void* g, void* l) {
    __builtin_amdgcn_global_load_lds((const AS1 uint32_t*)g, (AS3 uint32_t*)l, 16, 0, 0);
}
__device__ __forceinline__ void astore(u64* p, u64 v) {
    __hip_atomic_store(p, v, __ATOMIC_RELAXED, __HIP_MEMORY_SCOPE_AGENT);
}
#define SWZ(v, pat) __uint_as_float(__builtin_amdgcn_ds_swizzle(__float_as_uint(v), pat))
#define DPA(c, ctrl) c += __uint_as_float(__builtin_amdgcn_mov_dpp(__float_as_uint(c), ctrl, 0xF, 0xF, true))
// single-instruction f16(lo/hi of %1) * f32(%2) + f32 acc
#define FMIX_LO(acc, h2, w) asm("v_fma_mix_f32 %0, %1, %2, %0 op_sel:[0,0,0] op_sel_hi:[1,0,0]" : "+v"(acc) : "v"(h2), "v"(w))
#define FMIX_HI(acc, h2, w) asm("v_fma_mix_f32 %0, %1, %2, %0 op_sel:[1,0,0] op_sel_hi:[1,0,0]" : "+v"(acc) : "v"(h2), "v"(w))

__global__ void init_ws_kernel(uint32_t* __restrict__ flg, uint32_t* __restrict__ ht0) {
    size_t i = (size_t)blockIdx.x * blockDim.x + threadIdx.x;
    if (i < FLAG_ELEMS + PC_ELEMS) flg[i] = 0;
    if (i < HT_HALF / 2) ht0[i] = 0;   // zero h buffer 0 (h_{-1} = 0), u32 view
}

// one wave per destination row: ballot+popc packing of nonzero mask entries
__global__ void build_ell_kernel(const float* __restrict__ Whh, const float* __restrict__ mask,
                                 const float* __restrict__ Wih,
                                 uint32_t* __restrict__ ent, uint32_t* __restrict__ cnt) {
    int gw = (int)((blockIdx.x * blockDim.x + threadIdx.x) >> 6);
    int lane = threadIdx.x & 63;
    if (gw >= HH) return;
    const int d = gw;
    const int area = (d >= AH) ? 1 : 0;
    const float* mrow = mask + (size_t)d * HH + (size_t)area * AH;
    const float* wrow = Whh + (size_t)d * HH + (size_t)area * AH;
    uint32_t* erow = ent + (size_t)d * KMAX;
    uint32_t base = 0;
    for (int c0 = 0; c0 < AH; c0 += 64) {
        int c = c0 + lane;
        float m = mrow[c];
        bool pred = (m != 0.0f);
        uint64_t mk = __ballot(pred);
        if (pred) {
            uint32_t pos = base + (uint32_t)__popcll(mk & ((1ull << lane) - 1ull));
            if (pos < KMAX) erow[pos] = ((uint32_t)c << 16) | (uint32_t)f2h_bits(wrow[c] * m);
        }
        base += (uint32_t)__popcll(mk);
    }
    if (lane < NI) {   // fold input projection as extra "columns"
        uint32_t pos = base + (uint32_t)lane;
        if (pos < KMAX)
            erow[pos] = ((uint32_t)(COLS + lane) << 16) | (uint32_t)f2h_bits(Wih[(size_t)d * NI + lane]);
    }
    base += NI;
    if (lane == 0) cnt[d] = (base < KMAX) ? base : KMAX;
}

__global__ void xt_kernel(const float* __restrict__ x, uint16_t* __restrict__ xT2) {
    int i = blockIdx.x * blockDim.x + threadIdx.x;  // [t][i][b]
    if (i >= NT * NI * NBATCH) return;
    int b = i % NBATCH;
    int rest = i / NBATCH;
    int ii = rest % NI;
    int t = rest / NI;
    xT2[i] = f2h_bits(x[((size_t)b * NT + t) * NI + ii]);
}

__global__ __launch_bounds__(NTHREADS, 4) void rnn_kernel(
    const uint32_t* __restrict__ ent, const uint32_t* __restrict__ cnt,
    const uint16_t* __restrict__ xT2, uint16_t* __restrict__ hT,
    uint32_t* __restrict__ flg,
    const float* __restrict__ bih, const float* __restrict__ bhh,
    float* __restrict__ out)
{
    extern __shared__ char smem[];
    uint4* slab = (uint4*)smem;                  // [2][COLT] f16x8
    float* hnew = (float*)(smem + OFF_HNEW);     // [2][NRW][9]

    const int tid = threadIdx.x;
    const int G = blockIdx.x & 15, role = blockIdx.x >> 4;   // placement-independent
    const int a = G >> 3, g = G & 7;
    const int row0 = role * NRW;                 // area-local
    const size_t mySlot = ((size_t)G * NBLK_G + role) * 32;

    const int wv = tid >> 6, lane = tid & 63;
    const int ro = lane >> 3;          // 0..7 row within wave
    const int kq = lane & 7;           // 0..7 k-stripe
    const int r  = wv * 8 + ro;        // block-local row (valid for wv < 15)

    // ---- hoist step-invariant entries into VGPRs ----
    float wj[JSLOT];
    int   aj[JSLOT];
    float biasr = 0.f;
    int wm = 0;
    if (wv < 15) {
        const int gRow = a * AH + row0 + r;
        const int n = (int)cnt[gRow];
        biasr = bih[gRow] + bhh[gRow];
        int jmax = (n > kq) ? ((n - kq + 7) >> 3) : 0;
        const uint32_t* ep = ent + (size_t)gRow * KMAX;
        #pragma unroll
        for (int j = 0; j < JSLOT; ++j) {
            uint32_t e = (j < jmax) ? ep[kq + 8 * j] : 0u;
            aj[j] = (int)((e >> 16) * 16);           // byte offset within one slab buffer
            wj[j] = (j < jmax) ? lo16(e) : 0.0f;
        }
        wm = jmax;
        #pragma unroll
        for (int s = 1; s < 64; s <<= 1) {
            int ov = __shfl_xor(wm, s, 64);
            wm = (ov > wm) ? ov : wm;                // wave-uniform trip count
        }
    }

    for (int t = 0; t < NT; ++t) {
        const int cur = t & 1, nxt = cur ^ 1;
        // ---- x tail for this step (const data, DMA into current slab) ----
        if (wv == 0 && lane < NI)
            gll16(xT2 + ((size_t)t * NI + lane) * NBATCH + g * NB,
                  &slab[cur * COLT + COLS + lane]);
        // ---- per-wave poll + stage: wave w owns producer (role+w)&15 ----
        if (wv > 0 || t == 0) {
            const int p = (role + wv) & 15;
            if (t > 0) {
                const uint32_t* sl = flg + ((size_t)G * NBLK_G + p) * 32;
                int guard = 0;
                while (__hip_atomic_load(sl, __ATOMIC_RELAXED, __HIP_MEMORY_SCOPE_AGENT)
                       < (uint32_t)t && ++guard < (1 << 15))
                    __builtin_amdgcn_s_sleep(1);
            }
            const uint4* sp = (const uint4*)(hT + (size_t)cur * HT_HALF
                                             + ((size_t)G * AH + p * NRW) * NB);
            const int l2 = (lane < 56) ? (64 + lane) : lane;
            uint4 v0, v1;
            asm volatile("global_load_dwordx4 %0, %2, off sc0 sc1\n\t"
                         "global_load_dwordx4 %1, %3, off sc0 sc1\n\t"
                         "s_waitcnt vmcnt(0)"
                         : "=&v"(v0), "=&v"(v1)
                         : "v"(sp + lane), "v"(sp + l2)
                         : "memory");
            uint4* dst = slab + cur * COLT + p * NRW;
            dst[lane] = v0;
            dst[l2] = v1;
        }
        __syncthreads();   // slab[cur] complete (also drains x-tail DMA)

        // ---- out-writes for t-1 on wave 15 (idle during compute) ----
        if (wv == 15 && t > 0) {
            const float* hp = hnew + ((t - 1) & 1) * NRW * HNEW_PAD;
            for (int i = lane; i < NB * NRW; i += 64) {
                int bb = i / NRW, d = i - bb * NRW;
                out[(((size_t)(g * NB + bb)) * NT + (t - 1)) * HH + (size_t)a * AH + row0 + d]
                    = hp[d * HNEW_PAD + bb];
            }
        }

        // ---- compute ----
        if (wv < 15) {
            const char* sb = (const char*)(slab + cur * COLT);
            float c0 = 0.f, c1 = 0.f, c2 = 0.f, c3 = 0.f, c4 = 0.f, c5 = 0.f, c6 = 0.f, c7 = 0.f;
            #pragma unroll
            for (int j = 0; j < JSLOT; ++j) {
                if (j >= wm) break;
                const uint4 hv = *(const uint4*)(sb + aj[j]);
                const float wf = wj[j];
                FMIX_LO(c0, hv.x, wf); FMIX_HI(c1, hv.x, wf);
                FMIX_LO(c2, hv.y, wf); FMIX_HI(c3, hv.y, wf);
                FMIX_LO(c4, hv.z, wf); FMIX_HI(c5, hv.z, wf);
                FMIX_LO(c6, hv.w, wf); FMIX_HI(c7, hv.w, wf);
            }
            // reduce across kq: xor4 via ds_swizzle, xor2/xor1 via DPP quad_perm
            c0 += SWZ(c0, 0x101F); c1 += SWZ(c1, 0x101F); c2 += SWZ(c2, 0x101F); c3 += SWZ(c3, 0x101F);
            c4 += SWZ(c4, 0x101F); c5 += SWZ(c5, 0x101F); c6 += SWZ(c6, 0x101F); c7 += SWZ(c7, 0x101F);
            DPA(c0, 0x4E); DPA(c1, 0x4E); DPA(c2, 0x4E); DPA(c3, 0x4E);
            DPA(c4, 0x4E); DPA(c5, 0x4E); DPA(c6, 0x4E); DPA(c7, 0x4E);
            DPA(c0, 0xB1); DPA(c1, 0xB1); DPA(c2, 0xB1); DPA(c3, 0xB1);
            DPA(c4, 0xB1); DPA(c5, 0xB1); DPA(c6, 0xB1); DPA(c7, 0xB1);
            if (kq == 0) {
                float h0 = fmaxf(c0 + biasr, 0.f), h1 = fmaxf(c1 + biasr, 0.f);
                float h2 = fmaxf(c2 + biasr, 0.f), h3 = fmaxf(c3 + biasr, 0.f);
                float h4 = fmaxf(c4 + biasr, 0.f), h5 = fmaxf(c5 + biasr, 0.f);
                float h6 = fmaxf(c6 + biasr, 0.f), h7 = fmaxf(c7 + biasr, 0.f);
                uint4 pk;
                pk.x = pkrtz(h0, h1); pk.y = pkrtz(h2, h3);
                pk.z = pkrtz(h4, h5); pk.w = pkrtz(h6, h7);
                // coherent publish for the other 15 blocks
                u64* dst8 = (u64*)(hT + (size_t)nxt * HT_HALF
                                   + ((size_t)G * AH + row0 + r) * NB);
                astore(dst8,     ((u64)pk.y << 32) | pk.x);
                astore(dst8 + 1, ((u64)pk.w << 32) | pk.z);
                // self-copy straight into next slab (skip L3 for own rows)
                slab[nxt * COLT + row0 + r] = pk;
                float* hp = hnew + cur * NRW * HNEW_PAD + r * HNEW_PAD;
                hp[0] = h0; hp[1] = h1; hp[2] = h2; hp[3] = h3;
                hp[4] = h4; hp[5] = h5; hp[6] = h6; hp[7] = h7;
            }
        }
        __syncthreads();   // drains all astores (compiler vmcnt) + hnew complete

        if (tid == 0)
            __hip_atomic_store(flg + mySlot, (uint32_t)(t + 1), __ATOMIC_RELAXED,
                               __HIP_MEMORY_SCOPE_AGENT);
    }
    // ---- epilogue: output for the final step ----
    {
        const float* hp = hnew + ((NT - 1) & 1) * NRW * HNEW_PAD;
        for (int i = tid; i < NB * NRW; i += NTHREADS) {
            int bb = i / NRW, d = i - bb * NRW;
            out[(((size_t)(g * NB + bb)) * NT + (NT - 1)) * HH + (size_t)a * AH + row0 + d]
                = hp[d * HNEW_PAD + bb];
        }
    }
}

extern "C" void kernel_launch(void* const* d_in, const int* in_sizes, int n_in,
                              void* d_out, int out_size, void* d_ws, size_t ws_size,
                              hipStream_t stream)
{
    const float* x    = (const float*)d_in[0];
    const float* Wih  = (const float*)d_in[1];
    const float* bih  = (const float*)d_in[2];
    const float* Whh  = (const float*)d_in[3];
    const float* bhh  = (const float*)d_in[4];
    const float* mask = (const float*)d_in[5];
    float* out = (float*)d_out;

    char* ws = (char*)d_ws;
    uint32_t* ent = (uint32_t*)(ws);
    uint32_t* cnt = (uint32_t*)(ws + ENT_BYTES);
    uint16_t* xT2 = (uint16_t*)(ws + ENT_BYTES + CNT_BYTES);
    uint16_t* hT  = (uint16_t*)(ws + ENT_BYTES + CNT_BYTES + XT2_BYTES);
    uint32_t* flg = (uint32_t*)(ws + ENT_BYTES + CNT_BYTES + XT2_BYTES + HT_BYTES);

    init_ws_kernel<<<512, 256, 0, stream>>>(flg, (uint32_t*)hT);
    build_ell_kernel<<<(HH * 64 + 255) / 256, 256, 0, stream>>>(Whh, mask, Wih, ent, cnt);
    xt_kernel<<<(NT * NI * NBATCH + 255) / 256, 256, 0, stream>>>(x, xT2);

    hipFuncSetAttribute((const void*)rnn_kernel,
                        hipFuncAttributeMaxDynamicSharedMemorySize, SMEM_ALLOC);

    void* args[] = {(void*)&ent, (void*)&cnt, (void*)&xT2, (void*)&hT, (void*)&flg,
                    (void*)&bih, (void*)&bhh, (void*)&out};
    hipLaunchCooperativeKernel((const void*)rnn_kernel, dim3(NBLOCKS), dim3(NTHREADS),
                               args, SMEM_ALLOC, stream);
}